// Round 1
// baseline (5999.551 us; speedup 1.0000x reference)
//
#include <hip/hip_runtime.h>

// ---------------- workspace layout (float offsets) ----------------
#define WS_OFF_PATCHES 0ull                  // 12544*1024
#define WS_OFF_X       12845056ull           // 6422528 (enc x 3136x1024 / dec x 12544x512)
#define WS_OFF_LN      19267584ull           // 6422528
#define WS_OFF_QKV     25690112ull           // 19267584 (Xp / enc qkv / dec qkv / pred)
#define WS_OFF_HID     44957696ull           // 12845056 (att-o / mlp hidden / dec_tok / gathered)
#define WS_OFF_ORD     57802752ull           // 12544 ints
#define WS_OFF_PART    57815296ull           // 4096 floats

#define GF_ACC 1
#define GF_GELU 2

__device__ __forceinline__ float gelu_f(float x) {
    float x3 = x * x * x;
    float t = tanhf(0.7978845608028654f * (x + 0.044715f * x3));
    return 0.5f * x * (1.0f + t);
}

// Xp[row][k] = images patchified, row = b*196 + py*14+px, k = (r*16+c)*3+ch
__global__ __launch_bounds__(256) void patchify_kernel(const float* __restrict__ img,
                                                       float* __restrict__ Xp) {
    const long long total = 12544ll * 768;
    for (long long e = (long long)blockIdx.x * 256 + threadIdx.x; e < total;
         e += (long long)gridDim.x * 256) {
        int row = (int)(e / 768), k = (int)(e % 768);
        int b = row / 196, pi = row % 196;
        int py = pi / 14, px = pi % 14;
        int r = k / 48, rem = k % 48;
        int c = rem / 3, ch = rem % 3;
        long long src = (((long long)(b * 224 + py * 16 + r)) * 224 + (px * 16 + c)) * 3 + ch;
        Xp[e] = img[src];
    }
}

// C[MxN] = A[MxK] @ B[KxN] (+bias)(+gelu)(+=C). Row-major, M%64==0, N%64==0, K%16==0.
__global__ __launch_bounds__(256) void gemm_kernel(const float* __restrict__ A,
                                                   const float* __restrict__ B,
                                                   float* __restrict__ C,
                                                   const float* __restrict__ bias,
                                                   int M, int N, int K, int flags) {
    __shared__ float As[16][68];   // As[k][m]
    __shared__ float Bs[16][68];   // Bs[k][n]
    int tid = threadIdx.x;
    int row0 = blockIdx.y * 64, col0 = blockIdx.x * 64;
    int tx = tid & 15, ty = tid >> 4;
    int am = tid >> 2, ak = (tid & 3) << 2;   // A: row am, k ak..ak+3
    int bk = tid >> 4, bn = (tid & 15) << 2;  // B: row bk, col bn..bn+3
    float acc[4][4] = {};
    const float* Aptr = A + (size_t)(row0 + am) * K + ak;
    const float* Bptr = B + (size_t)bk * N + col0 + bn;
    for (int k0 = 0; k0 < K; k0 += 16) {
        float4 av = *(const float4*)(Aptr + k0);
        float4 bv = *(const float4*)(Bptr + (size_t)k0 * N);
        As[ak + 0][am] = av.x;
        As[ak + 1][am] = av.y;
        As[ak + 2][am] = av.z;
        As[ak + 3][am] = av.w;
        *(float4*)&Bs[bk][bn] = bv;
        __syncthreads();
#pragma unroll
        for (int k = 0; k < 16; ++k) {
            float4 a = *(const float4*)&As[k][ty << 2];
            float4 b = *(const float4*)&Bs[k][tx << 2];
            float ar[4] = {a.x, a.y, a.z, a.w};
            float br[4] = {b.x, b.y, b.z, b.w};
#pragma unroll
            for (int i = 0; i < 4; ++i)
#pragma unroll
                for (int j = 0; j < 4; ++j) acc[i][j] += ar[i] * br[j];
        }
        __syncthreads();
    }
#pragma unroll
    for (int i = 0; i < 4; ++i) {
        int r = row0 + (ty << 2) + i;
#pragma unroll
        for (int j = 0; j < 4; ++j) {
            int c = col0 + (tx << 2) + j;
            float v = acc[i][j];
            if (bias) v += bias[c];
            if (flags & GF_GELU) v = gelu_f(v);
            size_t o = (size_t)r * N + c;
            if (flags & GF_ACC)
                C[o] += v;
            else
                C[o] = v;
        }
    }
}

// stable ascending argsort of 196 values per batch (matches jnp.argsort)
__global__ __launch_bounds__(256) void argsort_kernel(const float* __restrict__ rnd,
                                                      int* __restrict__ ord) {
    __shared__ float vals[196];
    int b = blockIdx.x;
    int t = threadIdx.x;
    if (t < 196) vals[t] = rnd[b * 196 + t];
    __syncthreads();
    if (t < 196) {
        float v = vals[t];
        int rank = 0;
        for (int j = 0; j < 196; ++j) {
            float vj = vals[j];
            rank += (vj < v) || (vj == v && j < t);
        }
        ord[b * 196 + rank] = t;
    }
}

__global__ __launch_bounds__(256) void gather_unmasked(const float* __restrict__ patches,
                                                       const float* __restrict__ pos,
                                                       const int* __restrict__ ord,
                                                       float* __restrict__ xe) {
    int row = blockIdx.x;  // 0..3135
    int b = row / 49, i = row % 49;
    int src = ord[b * 196 + 147 + i];
    const float* pr = patches + ((size_t)(b * 196 + src) << 10);
    const float* pe = pos + ((size_t)src << 10);
    float* o = xe + ((size_t)row << 10);
    for (int d = threadIdx.x; d < 1024; d += 256) o[d] = pr[d] + pe[d];
}

__global__ __launch_bounds__(256) void ln_kernel(const float* __restrict__ x,
                                                 float* __restrict__ y,
                                                 const float* __restrict__ s,
                                                 const float* __restrict__ b, int L) {
    __shared__ float red[8];
    int row = blockIdx.x;
    const float* xr = x + (size_t)row * L;
    float sum = 0.f, sq = 0.f;
    for (int i = threadIdx.x; i < L; i += 256) {
        float v = xr[i];
        sum += v;
        sq += v * v;
    }
    for (int off = 32; off; off >>= 1) {
        sum += __shfl_xor(sum, off);
        sq += __shfl_xor(sq, off);
    }
    int wave = threadIdx.x >> 6, lane = threadIdx.x & 63;
    if (lane == 0) {
        red[wave] = sum;
        red[4 + wave] = sq;
    }
    __syncthreads();
    if (threadIdx.x == 0) {
        float ts = red[0] + red[1] + red[2] + red[3];
        float tq = red[4] + red[5] + red[6] + red[7];
        red[0] = ts;
        red[4] = tq;
    }
    __syncthreads();
    float mean = red[0] / L;
    float var = red[4] / L - mean * mean;
    float inv = rsqrtf(var + 1e-5f);
    float* yr = y + (size_t)row * L;
    for (int i = threadIdx.x; i < L; i += 256) yr[i] = (xr[i] - mean) * inv * s[i] + b[i];
}

// attention: one block per (b,h). K staged in LDS (pad 65), V read coalesced from global.
template <int N, int H, int SQ, int SO>
__global__ __launch_bounds__(256) void attn_kernel(const float* __restrict__ qkv,
                                                   float* __restrict__ out) {
    __shared__ float Ks[N * 65];
    __shared__ float Ps[4 * N];
    int b = blockIdx.x / H, h = blockIdx.x % H;
    const float* base = qkv + (size_t)b * N * SQ;
    int qoff = h * 64, koff = H * 64 + h * 64, voff = 2 * H * 64 + h * 64;
    for (int idx = threadIdx.x; idx < N * 64; idx += 256) {
        int t = idx >> 6, d = idx & 63;
        Ks[t * 65 + d] = base[(size_t)t * SQ + koff + d];
    }
    __syncthreads();
    int wave = threadIdx.x >> 6, lane = threadIdx.x & 63;
    constexpr int NJ = (N + 63) / 64;
    for (int qt = wave; qt < N; qt += 4) {
        const float* qrow = base + (size_t)qt * SQ + qoff;
        float s[NJ];
#pragma unroll
        for (int j = 0; j < NJ; ++j) s[j] = 0.f;
        for (int d = 0; d < 64; ++d) {
            float qd = qrow[d];
#pragma unroll
            for (int j = 0; j < NJ; ++j) {
                int kt = lane + (j << 6);
                if (kt < N) s[j] += qd * Ks[kt * 65 + d];
            }
        }
        float m = -1e30f;
#pragma unroll
        for (int j = 0; j < NJ; ++j) {
            int kt = lane + (j << 6);
            if (kt < N) m = fmaxf(m, s[j] * 0.125f);
        }
        for (int off = 32; off; off >>= 1) m = fmaxf(m, __shfl_xor(m, off));
        float sum = 0.f;
        float p[NJ];
#pragma unroll
        for (int j = 0; j < NJ; ++j) {
            int kt = lane + (j << 6);
            p[j] = (kt < N) ? expf(s[j] * 0.125f - m) : 0.f;
            sum += p[j];
        }
        for (int off = 32; off; off >>= 1) sum += __shfl_xor(sum, off);
        float inv = 1.f / sum;
#pragma unroll
        for (int j = 0; j < NJ; ++j) {
            int kt = lane + (j << 6);
            if (kt < N) Ps[wave * N + kt] = p[j] * inv;
        }
        float o = 0.f;
        const float* vbase = base + voff + lane;
        for (int kt = 0; kt < N; ++kt) o += Ps[wave * N + kt] * vbase[(size_t)kt * SQ];
        out[((size_t)b * N + qt) * SO + h * 64 + lane] = o;
    }
}

__global__ __launch_bounds__(256) void scatter_tokens(const float* __restrict__ dec_tok,
                                                      const float* __restrict__ dec_pos,
                                                      const float* __restrict__ mask_tok,
                                                      const int* __restrict__ ord,
                                                      float* __restrict__ all_tok) {
    int e = blockIdx.x;  // 0..12543
    int b = e / 196, i = e % 196;
    int idx = ord[e];
    float* o = all_tok + ((size_t)(b * 196 + idx)) * 512;
    const float* dp = dec_pos + (size_t)idx * 512;
    if (i < 147) {
        for (int d = threadIdx.x; d < 512; d += 256) o[d] = mask_tok[d] + dp[d];
    } else {
        const float* dt = dec_tok + ((size_t)(b * 49 + (i - 147))) * 512;
        for (int d = threadIdx.x; d < 512; d += 256) o[d] = dt[d] + dp[d];
    }
}

__global__ __launch_bounds__(256) void gather_masked(const float* __restrict__ x,
                                                     const int* __restrict__ ord,
                                                     float* __restrict__ gm) {
    int r = blockIdx.x;  // 0..9407
    int b = r / 147, j = r % 147;
    int idx = ord[b * 196 + j];
    const float* src = x + ((size_t)(b * 196 + idx)) * 512;
    float* o = gm + (size_t)r * 512;
    for (int d = threadIdx.x; d < 512; d += 256) o[d] = src[d];
}

__global__ __launch_bounds__(256) void loss_partial(const float* __restrict__ pred,
                                                    const float* __restrict__ patches,
                                                    const int* __restrict__ ord,
                                                    float* __restrict__ part) {
    __shared__ float red[8];
    float local = 0.f;
    const long long total = 9633792ll;  // 9408*1024
    for (long long e = (long long)blockIdx.x * 256 + threadIdx.x; e < total; e += 4096ll * 256) {
        int r = (int)(e >> 10), d = (int)(e & 1023);
        int b = r / 147, j = r % 147;
        int idx = ord[b * 196 + j];
        float t = patches[(((size_t)(b * 196 + idx)) << 10) + d];
        float df = pred[e] - t;
        local += df * df;
    }
    for (int off = 32; off; off >>= 1) local += __shfl_xor(local, off);
    int wave = threadIdx.x >> 6, lane = threadIdx.x & 63;
    if (lane == 0) red[wave] = local;
    __syncthreads();
    if (threadIdx.x == 0) part[blockIdx.x] = red[0] + red[1] + red[2] + red[3];
}

__global__ __launch_bounds__(256) void loss_final(const float* __restrict__ part,
                                                  float* __restrict__ out) {
    __shared__ float red[8];
    float local = 0.f;
    for (int i = threadIdx.x; i < 4096; i += 256) local += part[i];
    for (int off = 32; off; off >>= 1) local += __shfl_xor(local, off);
    int wave = threadIdx.x >> 6, lane = threadIdx.x & 63;
    if (lane == 0) red[wave] = local;
    __syncthreads();
    if (threadIdx.x == 0) out[0] = (red[0] + red[1] + red[2] + red[3]) / 9633792.0f;
}

extern "C" void kernel_launch(void* const* d_in, const int* in_sizes, int n_in, void* d_out,
                              int out_size, void* d_ws, size_t ws_size, hipStream_t stream) {
    const float* images = (const float*)d_in[0];
    const float* rnd = (const float*)d_in[1];
    const float* patch_W = (const float*)d_in[2];
    const float* patch_b = (const float*)d_in[3];
    const float* pos_emb = (const float*)d_in[4];
    const float* enc_ln1s = (const float*)d_in[5];
    const float* enc_ln1b = (const float*)d_in[6];
    const float* enc_Wqkv = (const float*)d_in[7];
    const float* enc_Wo = (const float*)d_in[8];
    const float* enc_ln2s = (const float*)d_in[9];
    const float* enc_ln2b = (const float*)d_in[10];
    const float* enc_W1 = (const float*)d_in[11];
    const float* enc_b1 = (const float*)d_in[12];
    const float* enc_W2 = (const float*)d_in[13];
    const float* enc_b2 = (const float*)d_in[14];
    const float* enc_lnfs = (const float*)d_in[15];
    const float* enc_lnfb = (const float*)d_in[16];
    const float* e2d_W = (const float*)d_in[17];
    const float* e2d_b = (const float*)d_in[18];
    const float* mask_tok = (const float*)d_in[19];
    const float* dec_pos = (const float*)d_in[20];
    const float* dec_ln1s = (const float*)d_in[21];
    const float* dec_ln1b = (const float*)d_in[22];
    const float* dec_Wqkv = (const float*)d_in[23];
    const float* dec_Wo = (const float*)d_in[24];
    const float* dec_ln2s = (const float*)d_in[25];
    const float* dec_ln2b = (const float*)d_in[26];
    const float* dec_W1 = (const float*)d_in[27];
    const float* dec_b1 = (const float*)d_in[28];
    const float* dec_W2 = (const float*)d_in[29];
    const float* dec_b2 = (const float*)d_in[30];
    const float* dec_lnfs = (const float*)d_in[31];
    const float* dec_lnfb = (const float*)d_in[32];
    const float* pix_W = (const float*)d_in[33];
    const float* pix_b = (const float*)d_in[34];

    float* ws = (float*)d_ws;
    float* patches = ws + WS_OFF_PATCHES;
    float* Rx = ws + WS_OFF_X;
    float* Rln = ws + WS_OFF_LN;
    float* Rqkv = ws + WS_OFF_QKV;
    float* Rhid = ws + WS_OFF_HID;
    int* ord = (int*)(ws + WS_OFF_ORD);
    float* part = ws + WS_OFF_PART;
    float* out = (float*)d_out;

    // 1) patchify into Rqkv (Xp: 12544x768), then patches = Xp @ patch_W + patch_b
    patchify_kernel<<<4096, 256, 0, stream>>>(images, Rqkv);
    gemm_kernel<<<dim3(1024 / 64, 12544 / 64), 256, 0, stream>>>(Rqkv, patch_W, patches,
                                                                 patch_b, 12544, 1024, 768, 0);
    // 2) per-batch stable argsort of rand
    argsort_kernel<<<64, 256, 0, stream>>>(rnd, ord);
    // 3) gather unmasked tokens (patches + pos_emb)
    gather_unmasked<<<3136, 256, 0, stream>>>(patches, pos_emb, ord, Rx);

    // 4) encoder: 2 layers, dim 1024, heads 16
    for (int l = 0; l < 2; ++l) {
        ln_kernel<<<3136, 256, 0, stream>>>(Rx, Rln, enc_ln1s + l * 1024, enc_ln1b + l * 1024,
                                            1024);
        gemm_kernel<<<dim3(3072 / 64, 3136 / 64), 256, 0, stream>>>(
            Rln, enc_Wqkv + (size_t)l * 1024 * 3072, Rqkv, nullptr, 3136, 3072, 1024, 0);
        attn_kernel<49, 16, 3072, 1024><<<64 * 16, 256, 0, stream>>>(Rqkv, Rhid);
        gemm_kernel<<<dim3(1024 / 64, 3136 / 64), 256, 0, stream>>>(
            Rhid, enc_Wo + (size_t)l * 1024 * 1024, Rx, nullptr, 3136, 1024, 1024, GF_ACC);
        ln_kernel<<<3136, 256, 0, stream>>>(Rx, Rln, enc_ln2s + l * 1024, enc_ln2b + l * 1024,
                                            1024);
        gemm_kernel<<<dim3(4096 / 64, 3136 / 64), 256, 0, stream>>>(
            Rln, enc_W1 + (size_t)l * 1024 * 4096, Rhid, enc_b1 + l * 4096, 3136, 4096, 1024,
            GF_GELU);
        gemm_kernel<<<dim3(1024 / 64, 3136 / 64), 256, 0, stream>>>(
            Rhid, enc_W2 + (size_t)l * 4096 * 1024, Rx, enc_b2 + l * 1024, 3136, 1024, 4096,
            GF_ACC);
    }
    ln_kernel<<<3136, 256, 0, stream>>>(Rx, Rln, enc_lnfs, enc_lnfb, 1024);

    // 5) e2d projection + scatter with mask tokens + dec_pos
    gemm_kernel<<<dim3(512 / 64, 3136 / 64), 256, 0, stream>>>(Rln, e2d_W, Rhid, e2d_b, 3136,
                                                               512, 1024, 0);
    scatter_tokens<<<12544, 256, 0, stream>>>(Rhid, dec_pos, mask_tok, ord, Rx);

    // 6) decoder: 1 layer, dim 512, heads 8 (MLP chunked x2 rows)
    ln_kernel<<<12544, 256, 0, stream>>>(Rx, Rln, dec_ln1s, dec_ln1b, 512);
    gemm_kernel<<<dim3(1536 / 64, 12544 / 64), 256, 0, stream>>>(Rln, dec_Wqkv, Rqkv, nullptr,
                                                                 12544, 1536, 512, 0);
    attn_kernel<196, 8, 1536, 512><<<64 * 8, 256, 0, stream>>>(Rqkv, Rhid);
    gemm_kernel<<<dim3(512 / 64, 12544 / 64), 256, 0, stream>>>(Rhid, dec_Wo, Rx, nullptr,
                                                                12544, 512, 512, GF_ACC);
    ln_kernel<<<12544, 256, 0, stream>>>(Rx, Rln, dec_ln2s, dec_ln2b, 512);
    for (int c = 0; c < 2; ++c) {
        size_t ro = (size_t)c * 6272;
        gemm_kernel<<<dim3(2048 / 64, 6272 / 64), 256, 0, stream>>>(
            Rln + ro * 512, dec_W1, Rhid, dec_b1, 6272, 2048, 512, GF_GELU);
        gemm_kernel<<<dim3(512 / 64, 6272 / 64), 256, 0, stream>>>(
            Rhid, dec_W2, Rx + ro * 512, dec_b2, 6272, 512, 2048, GF_ACC);
    }
    ln_kernel<<<12544, 256, 0, stream>>>(Rx, Rln, dec_lnfs, dec_lnfb, 512);

    // 7) gather masked rows, pix head, MSE loss
    gather_masked<<<9408, 256, 0, stream>>>(Rln, ord, Rhid);
    gemm_kernel<<<dim3(1024 / 64, 9408 / 64), 256, 0, stream>>>(Rhid, pix_W, Rqkv, pix_b, 9408,
                                                                1024, 512, 0);
    loss_partial<<<4096, 256, 0, stream>>>(Rqkv, patches, ord, part);
    loss_final<<<1, 256, 0, stream>>>(part, out);
}

// Round 2
// 2569.780 us; speedup vs baseline: 2.3347x; 2.3347x over previous
//
#include <hip/hip_runtime.h>

typedef __attribute__((ext_vector_type(8))) __bf16 bf16x8;
typedef __attribute__((ext_vector_type(4))) float f32x4;

// ---------------- workspace layout (byte offsets) ----------------
#define OFF_PATCH 0ull          // bf16 12544x1024
#define OFF_X     25690112ull   // f32  max(3200x1024, 12544x512)
#define OFF_LN    51380224ull   // bf16 max(3200x1024, 12544x512)
#define OFF_QKV   64225280ull   // bf16 qkv / f32 dec_tok / f32 pred (38,797,312 B)
#define OFF_HID   103022592ull  // bf16 max(12544x2048) (51,380,224 B)
#define OFF_WP    154402816ull  // bf16 packed transposed weights (60,293,120 B)
#define OFF_ORD   214695936ull  // int 12544
#define OFF_PART  214746112ull  // f32 4096

// bf16-element offsets inside packed-weight region
#define WP_PATCH   0ull
#define WP_ENC_QKV 786432ull
#define WP_ENC_WO  7077888ull
#define WP_ENC_W1  9175040ull
#define WP_ENC_W2  17563648ull
#define WP_E2D     25952256ull
#define WP_DEC_QKV 26476544ull
#define WP_DEC_WO  27262976ull
#define WP_DEC_W1  27525120ull
#define WP_DEC_W2  28573696ull
#define WP_PIX     29622272ull

#define OM_BF16 0
#define OM_F32  1
#define OM_ACC  2
#define OM_GELU 3

__device__ __forceinline__ float b2f(unsigned short u) {
    return __uint_as_float(((unsigned int)u) << 16);
}
__device__ __forceinline__ unsigned short f2b(float f) {
    unsigned int x = __float_as_uint(f);
    x += 0x7fffu + ((x >> 16) & 1u);
    return (unsigned short)(x >> 16);
}
__device__ __forceinline__ float gelu_f(float x) {
    float x3 = x * x * x;
    float t = tanhf(0.7978845608028654f * (x + 0.044715f * x3));
    return 0.5f * x * (1.0f + t);
}

// ---------------- weight pack: W[K][N] f32 -> Wt[N][K] bf16 ----------------
__global__ __launch_bounds__(256) void pack_w(const float* __restrict__ in,
                                              unsigned short* __restrict__ out, int K, int N) {
    __shared__ float tile[32][33];
    int kt = blockIdx.y * 32, nt = blockIdx.x * 32;
    int tx = threadIdx.x & 31, ty = threadIdx.x >> 5;  // 32 x 8
#pragma unroll
    for (int i = 0; i < 32; i += 8) tile[ty + i][tx] = in[(size_t)(kt + ty + i) * N + nt + tx];
    __syncthreads();
#pragma unroll
    for (int i = 0; i < 32; i += 8)
        out[(size_t)(nt + ty + i) * K + kt + tx] = f2b(tile[tx][ty + i]);
}

// ---------------- patchify: images -> Xp bf16 [12544][768] ----------------
__global__ __launch_bounds__(256) void patchify_kernel(const float* __restrict__ img,
                                                       unsigned short* __restrict__ Xp) {
    const long long total = 12544ll * 768;
    for (long long e = (long long)blockIdx.x * 256 + threadIdx.x; e < total;
         e += (long long)gridDim.x * 256) {
        int row = (int)(e / 768), k = (int)(e % 768);
        int b = row / 196, pi = row % 196;
        int py = pi / 14, px = pi % 14;
        int r = k / 48, rem = k % 48;
        int c = rem / 3, ch = rem % 3;
        long long src = (((long long)(b * 224 + py * 16 + r)) * 224 + (px * 16 + c)) * 3 + ch;
        Xp[e] = f2b(img[src]);
    }
}

// ---------------- MFMA GEMM: C[MxN] = A[MxK](bf16) @ Bt[NxK](bf16)^T ----------------
// 128x128 tile, BK=64, 4 waves, each wave 64x64 (4x4 frags of 16x16x32).
template <int OM>
__global__ __launch_bounds__(256) void gemm_mfma(const unsigned short* __restrict__ A,
                                                 const unsigned short* __restrict__ Bt,
                                                 void* __restrict__ Cv,
                                                 const float* __restrict__ bias,
                                                 int M, int N, int K) {
    __shared__ __align__(16) unsigned short As[128 * 64];
    __shared__ __align__(16) unsigned short Bs[128 * 64];
    const int tid = threadIdx.x;
    const int wave = tid >> 6, lane = tid & 63;
    const int brow = blockIdx.y * 128, bcol = blockIdx.x * 128;
    const int r0 = tid >> 3;         // 0..31
    const int c16 = (tid & 7) * 8;   // 0,8,...,56
    f32x4 acc[4][4];
#pragma unroll
    for (int m = 0; m < 4; ++m)
#pragma unroll
        for (int n = 0; n < 4; ++n) acc[m][n] = (f32x4){0.f, 0.f, 0.f, 0.f};

    const int wr = (wave >> 1) * 64, wc = (wave & 1) * 64;
    const int fr = lane & 15, fq = lane >> 4;

    const unsigned short* Ag = A + (size_t)(brow + r0) * K + c16;
    const unsigned short* Bg = Bt + (size_t)(bcol + r0) * K + c16;

    for (int k0 = 0; k0 < K; k0 += 64) {
        uint4 av[4], bv[4];
#pragma unroll
        for (int i = 0; i < 4; ++i) {
            av[i] = *(const uint4*)(Ag + (size_t)(i * 32) * K + k0);
            bv[i] = *(const uint4*)(Bg + (size_t)(i * 32) * K + k0);
        }
        __syncthreads();
#pragma unroll
        for (int i = 0; i < 4; ++i) {
            *(uint4*)&As[(i * 32 + r0) * 64 + c16] = av[i];
            *(uint4*)&Bs[(i * 32 + r0) * 64 + c16] = bv[i];
        }
        __syncthreads();
#pragma unroll
        for (int kk = 0; kk < 2; ++kk) {
            bf16x8 af[4], bfr[4];
#pragma unroll
            for (int m = 0; m < 4; ++m)
                af[m] = *(const bf16x8*)&As[(wr + m * 16 + fr) * 64 + kk * 32 + fq * 8];
#pragma unroll
            for (int n = 0; n < 4; ++n)
                bfr[n] = *(const bf16x8*)&Bs[(wc + n * 16 + fr) * 64 + kk * 32 + fq * 8];
#pragma unroll
            for (int m = 0; m < 4; ++m)
#pragma unroll
                for (int n = 0; n < 4; ++n)
                    acc[m][n] = __builtin_amdgcn_mfma_f32_16x16x32_bf16(af[m], bfr[n],
                                                                       acc[m][n], 0, 0, 0);
        }
    }
#pragma unroll
    for (int m = 0; m < 4; ++m) {
        int rbase = brow + wr + m * 16 + fq * 4;
#pragma unroll
        for (int r = 0; r < 4; ++r) {
            int row = rbase + r;
            if (row < M) {
#pragma unroll
                for (int n = 0; n < 4; ++n) {
                    int col = bcol + wc + n * 16 + fr;
                    float v = acc[m][n][r];
                    if (bias) v += bias[col];
                    size_t o = (size_t)row * N + col;
                    if constexpr (OM == OM_BF16) ((unsigned short*)Cv)[o] = f2b(v);
                    else if constexpr (OM == OM_F32) ((float*)Cv)[o] = v;
                    else if constexpr (OM == OM_ACC) ((float*)Cv)[o] += v;
                    else ((unsigned short*)Cv)[o] = f2b(gelu_f(v));
                }
            }
        }
    }
}

// ---------------- stable argsort of 196 per batch ----------------
__global__ __launch_bounds__(256) void argsort_kernel(const float* __restrict__ rnd,
                                                      int* __restrict__ ord) {
    __shared__ float vals[196];
    int b = blockIdx.x, t = threadIdx.x;
    if (t < 196) vals[t] = rnd[b * 196 + t];
    __syncthreads();
    if (t < 196) {
        float v = vals[t];
        int rank = 0;
        for (int j = 0; j < 196; ++j) {
            float vj = vals[j];
            rank += (vj < v) || (vj == v && j < t);
        }
        ord[b * 196 + rank] = t;
    }
}

__global__ __launch_bounds__(256) void gather_unmasked(const unsigned short* __restrict__ patches,
                                                       const float* __restrict__ pos,
                                                       const int* __restrict__ ord,
                                                       float* __restrict__ xe) {
    int row = blockIdx.x;  // 0..3135
    int b = row / 49, i = row % 49;
    int src = ord[b * 196 + 147 + i];
    const unsigned short* pr = patches + ((size_t)(b * 196 + src) << 10);
    const float* pe = pos + ((size_t)src << 10);
    float* o = xe + ((size_t)row << 10);
    int d = threadIdx.x * 4;
    ushort4 pv = *(const ushort4*)(pr + d);
    float4 p4 = *(const float4*)(pe + d);
    float4 r;
    r.x = b2f(pv.x) + p4.x; r.y = b2f(pv.y) + p4.y;
    r.z = b2f(pv.z) + p4.z; r.w = b2f(pv.w) + p4.w;
    *(float4*)(o + d) = r;
}

// ---------------- LayerNorm: f32 in -> bf16 out ----------------
template <int L>
__global__ __launch_bounds__(256) void ln_kernel(const float* __restrict__ x,
                                                 unsigned short* __restrict__ y,
                                                 const float* __restrict__ sw,
                                                 const float* __restrict__ bw) {
    __shared__ float red[8];
    const int tid = threadIdx.x;
    const float* xr = x + (size_t)blockIdx.x * L;
    float sum = 0.f, sq = 0.f;
    for (int i = tid * 4; i < L; i += 1024) {
        float4 v = *(const float4*)(xr + i);
        sum += v.x + v.y + v.z + v.w;
        sq += v.x * v.x + v.y * v.y + v.z * v.z + v.w * v.w;
    }
    for (int off = 32; off; off >>= 1) {
        sum += __shfl_xor(sum, off);
        sq += __shfl_xor(sq, off);
    }
    int wave = tid >> 6, lane = tid & 63;
    if (lane == 0) { red[wave] = sum; red[4 + wave] = sq; }
    __syncthreads();
    float ts = red[0] + red[1] + red[2] + red[3];
    float tq = red[4] + red[5] + red[6] + red[7];
    float mean = ts / L;
    float inv = rsqrtf(tq / L - mean * mean + 1e-5f);
    unsigned short* yr = y + (size_t)blockIdx.x * L;
    for (int i = tid * 4; i < L; i += 1024) {
        float4 v = *(const float4*)(xr + i);
        float4 s4 = *(const float4*)(sw + i);
        float4 b4 = *(const float4*)(bw + i);
        ushort4 o;
        o.x = f2b((v.x - mean) * inv * s4.x + b4.x);
        o.y = f2b((v.y - mean) * inv * s4.y + b4.y);
        o.z = f2b((v.z - mean) * inv * s4.z + b4.z);
        o.w = f2b((v.w - mean) * inv * s4.w + b4.w);
        *(ushort4*)(yr + i) = o;
    }
}

// ---------------- attention: one block per (b,h); K/V LDS-resident ----------------
template <int N, int H>
__global__ __launch_bounds__(256) void attn_kernel(const unsigned short* __restrict__ qkv,
                                                   unsigned short* __restrict__ out) {
    constexpr int SQ = 3 * H * 64, SO = H * 64;
    constexpr int NJ = (N + 63) / 64;
    __shared__ __align__(16) unsigned int Ku[N * 33];    // 2 bf16 per uint, stride 33 (bank-clean)
    __shared__ __align__(16) unsigned short Vs[N * 64];
    __shared__ float qs[4][64];
    __shared__ float Ps[4][NJ * 64];
    int b = blockIdx.x / H, h = blockIdx.x % H;
    const unsigned short* base = qkv + (size_t)b * N * SQ;
    const int qoff = h * 64, koff = (H + h) * 64, voff = (2 * H + h) * 64;
    for (int idx = threadIdx.x; idx < N * 16; idx += 256) {
        int t = idx >> 4, c = (idx & 15) * 4;
        uint2 kv = *(const uint2*)(base + (size_t)t * SQ + koff + c);
        Ku[t * 33 + (c >> 1)] = kv.x;
        Ku[t * 33 + (c >> 1) + 1] = kv.y;
        *(uint2*)&Vs[t * 64 + c] = *(const uint2*)(base + (size_t)t * SQ + voff + c);
    }
    __syncthreads();
    int wave = threadIdx.x >> 6, lane = threadIdx.x & 63;
    const unsigned int* kub[NJ];
    bool valid[NJ];
#pragma unroll
    for (int j = 0; j < NJ; ++j) {
        int kt = lane + j * 64;
        valid[j] = kt < N;
        kub[j] = &Ku[(valid[j] ? kt : 0) * 33];
    }
    for (int qt = wave; qt < N; qt += 4) {
        qs[wave][lane] = b2f(base[(size_t)qt * SQ + qoff + lane]);
        float s[NJ];
#pragma unroll
        for (int j = 0; j < NJ; ++j) s[j] = 0.f;
#pragma unroll 4
        for (int d2 = 0; d2 < 32; ++d2) {
            float2 q2 = *(const float2*)&qs[wave][d2 * 2];
#pragma unroll
            for (int j = 0; j < NJ; ++j) {
                unsigned int kk = kub[j][d2];
                s[j] += q2.x * __uint_as_float(kk << 16);
                s[j] += q2.y * __uint_as_float(kk & 0xffff0000u);
            }
        }
        float mx = -1e30f;
#pragma unroll
        for (int j = 0; j < NJ; ++j) {
            s[j] *= 0.125f;
            if (valid[j]) mx = fmaxf(mx, s[j]);
        }
        for (int off = 32; off; off >>= 1) mx = fmaxf(mx, __shfl_xor(mx, off));
        float sum = 0.f, p[NJ];
#pragma unroll
        for (int j = 0; j < NJ; ++j) {
            p[j] = valid[j] ? __expf(s[j] - mx) : 0.f;
            sum += p[j];
        }
        for (int off = 32; off; off >>= 1) sum += __shfl_xor(sum, off);
        float inv = 1.f / sum;
#pragma unroll
        for (int j = 0; j < NJ; ++j) Ps[wave][lane + j * 64] = p[j] * inv;
        float o = 0.f;
#pragma unroll 4
        for (int kt = 0; kt < N; ++kt) o += Ps[wave][kt] * b2f(Vs[kt * 64 + lane]);
        out[((size_t)b * N + qt) * SO + h * 64 + lane] = f2b(o);
    }
}

__global__ __launch_bounds__(256) void scatter_tokens(const float* __restrict__ dec_tok,
                                                      const float* __restrict__ dec_pos,
                                                      const float* __restrict__ mask_tok,
                                                      const int* __restrict__ ord,
                                                      float* __restrict__ all_tok) {
    int e = blockIdx.x;  // 0..12543
    int b = e / 196, i = e % 196;
    int idx = ord[e];
    float* o = all_tok + ((size_t)(b * 196 + idx)) * 512;
    const float* dp = dec_pos + (size_t)idx * 512;
    int d = threadIdx.x * 4;
    if (d < 512) {
        float4 dv = *(const float4*)(dp + d);
        float4 sv;
        if (i < 147) sv = *(const float4*)(mask_tok + d);
        else sv = *(const float4*)(dec_tok + ((size_t)(b * 49 + (i - 147))) * 512 + d);
        float4 r = {sv.x + dv.x, sv.y + dv.y, sv.z + dv.z, sv.w + dv.w};
        *(float4*)(o + d) = r;
    }
}

__global__ __launch_bounds__(256) void gather_masked(const unsigned short* __restrict__ x,
                                                     const int* __restrict__ ord,
                                                     unsigned short* __restrict__ gm) {
    int r = blockIdx.x;  // 0..9407
    int b = r / 147, j = r % 147;
    int idx = ord[b * 196 + j];
    const unsigned short* src = x + ((size_t)(b * 196 + idx)) * 512;
    unsigned short* o = gm + (size_t)r * 512;
    int d = threadIdx.x * 4;
    if (d < 512) *(ushort4*)(o + d) = *(const ushort4*)(src + d);
}

__global__ __launch_bounds__(256) void loss_partial(const float* __restrict__ pred,
                                                    const unsigned short* __restrict__ patches,
                                                    const int* __restrict__ ord,
                                                    float* __restrict__ part) {
    __shared__ float red[8];
    float local = 0.f;
    const long long total = 9633792ll;  // 9408*1024
    for (long long e = (long long)blockIdx.x * 256 + threadIdx.x; e < total; e += 4096ll * 256) {
        int r = (int)(e >> 10), d = (int)(e & 1023);
        int b = r / 147, j = r % 147;
        int idx = ord[b * 196 + j];
        float t = b2f(patches[(((size_t)(b * 196 + idx)) << 10) + d]);
        float df = pred[e] - t;
        local += df * df;
    }
    for (int off = 32; off; off >>= 1) local += __shfl_xor(local, off);
    int wave = threadIdx.x >> 6, lane = threadIdx.x & 63;
    if (lane == 0) red[wave] = local;
    __syncthreads();
    if (threadIdx.x == 0) part[blockIdx.x] = red[0] + red[1] + red[2] + red[3];
}

__global__ __launch_bounds__(256) void loss_final(const float* __restrict__ part,
                                                  float* __restrict__ out) {
    __shared__ float red[8];
    float local = 0.f;
    for (int i = threadIdx.x; i < 4096; i += 256) local += part[i];
    for (int off = 32; off; off >>= 1) local += __shfl_xor(local, off);
    int wave = threadIdx.x >> 6, lane = threadIdx.x & 63;
    if (lane == 0) red[wave] = local;
    __syncthreads();
    if (threadIdx.x == 0) out[0] = (red[0] + red[1] + red[2] + red[3]) / 9633792.0f;
}

extern "C" void kernel_launch(void* const* d_in, const int* in_sizes, int n_in, void* d_out,
                              int out_size, void* d_ws, size_t ws_size, hipStream_t stream) {
    const float* images = (const float*)d_in[0];
    const float* rnd = (const float*)d_in[1];
    const float* patch_W = (const float*)d_in[2];
    const float* patch_b = (const float*)d_in[3];
    const float* pos_emb = (const float*)d_in[4];
    const float* enc_ln1s = (const float*)d_in[5];
    const float* enc_ln1b = (const float*)d_in[6];
    const float* enc_Wqkv = (const float*)d_in[7];
    const float* enc_Wo = (const float*)d_in[8];
    const float* enc_ln2s = (const float*)d_in[9];
    const float* enc_ln2b = (const float*)d_in[10];
    const float* enc_W1 = (const float*)d_in[11];
    const float* enc_b1 = (const float*)d_in[12];
    const float* enc_W2 = (const float*)d_in[13];
    const float* enc_b2 = (const float*)d_in[14];
    const float* enc_lnfs = (const float*)d_in[15];
    const float* enc_lnfb = (const float*)d_in[16];
    const float* e2d_W = (const float*)d_in[17];
    const float* e2d_b = (const float*)d_in[18];
    const float* mask_tok = (const float*)d_in[19];
    const float* dec_pos = (const float*)d_in[20];
    const float* dec_ln1s = (const float*)d_in[21];
    const float* dec_ln1b = (const float*)d_in[22];
    const float* dec_Wqkv = (const float*)d_in[23];
    const float* dec_Wo = (const float*)d_in[24];
    const float* dec_ln2s = (const float*)d_in[25];
    const float* dec_ln2b = (const float*)d_in[26];
    const float* dec_W1 = (const float*)d_in[27];
    const float* dec_b1 = (const float*)d_in[28];
    const float* dec_W2 = (const float*)d_in[29];
    const float* dec_b2 = (const float*)d_in[30];
    const float* dec_lnfs = (const float*)d_in[31];
    const float* dec_lnfb = (const float*)d_in[32];
    const float* pix_W = (const float*)d_in[33];
    const float* pix_b = (const float*)d_in[34];

    char* ws = (char*)d_ws;
    unsigned short* patches = (unsigned short*)(ws + OFF_PATCH);
    float* Rx = (float*)(ws + OFF_X);
    unsigned short* Rln = (unsigned short*)(ws + OFF_LN);
    unsigned short* RqkvB = (unsigned short*)(ws + OFF_QKV);
    float* RqkvF = (float*)(ws + OFF_QKV);
    unsigned short* Rhid = (unsigned short*)(ws + OFF_HID);
    unsigned short* wp = (unsigned short*)(ws + OFF_WP);
    int* ord = (int*)(ws + OFF_ORD);
    float* part = (float*)(ws + OFF_PART);
    float* out = (float*)d_out;

    // ---- pack all weights: [K][N] f32 -> [N][K] bf16 ----
    auto PACK = [&](const float* src, size_t wpo, int K, int N) {
        pack_w<<<dim3(N / 32, K / 32), 256, 0, stream>>>(src, wp + wpo, K, N);
    };
    PACK(patch_W, WP_PATCH, 768, 1024);
    for (int l = 0; l < 2; ++l) {
        PACK(enc_Wqkv + (size_t)l * 1024 * 3072, WP_ENC_QKV + (size_t)l * 3145728, 1024, 3072);
        PACK(enc_Wo + (size_t)l * 1024 * 1024, WP_ENC_WO + (size_t)l * 1048576, 1024, 1024);
        PACK(enc_W1 + (size_t)l * 1024 * 4096, WP_ENC_W1 + (size_t)l * 4194304, 1024, 4096);
        PACK(enc_W2 + (size_t)l * 4096 * 1024, WP_ENC_W2 + (size_t)l * 4194304, 4096, 1024);
    }
    PACK(e2d_W, WP_E2D, 1024, 512);
    PACK(dec_Wqkv, WP_DEC_QKV, 512, 1536);
    PACK(dec_Wo, WP_DEC_WO, 512, 512);
    PACK(dec_W1, WP_DEC_W1, 512, 2048);
    PACK(dec_W2, WP_DEC_W2, 2048, 512);
    PACK(pix_W, WP_PIX, 512, 1024);

    auto GEMM = [&](int om, const unsigned short* A, size_t wpo, void* C, const float* bias,
                    int M, int N, int K) {
        dim3 g(N / 128, (M + 127) / 128);
        const unsigned short* Bt = wp + wpo;
        if (om == OM_BF16) gemm_mfma<OM_BF16><<<g, 256, 0, stream>>>(A, Bt, C, bias, M, N, K);
        else if (om == OM_F32) gemm_mfma<OM_F32><<<g, 256, 0, stream>>>(A, Bt, C, bias, M, N, K);
        else if (om == OM_ACC) gemm_mfma<OM_ACC><<<g, 256, 0, stream>>>(A, Bt, C, bias, M, N, K);
        else gemm_mfma<OM_GELU><<<g, 256, 0, stream>>>(A, Bt, C, bias, M, N, K);
    };

    // 1) patchify (Xp bf16 in Rhid), patches = Xp @ patch_W + b  (bf16)
    patchify_kernel<<<4096, 256, 0, stream>>>(images, Rhid);
    GEMM(OM_BF16, Rhid, WP_PATCH, patches, patch_b, 12544, 1024, 768);
    // 2) argsort + gather unmasked (fp32 residual stream)
    argsort_kernel<<<64, 256, 0, stream>>>(rnd, ord);
    gather_unmasked<<<3136, 256, 0, stream>>>(patches, pos_emb, ord, Rx);

    // 3) encoder
    for (int l = 0; l < 2; ++l) {
        ln_kernel<1024><<<3136, 256, 0, stream>>>(Rx, Rln, enc_ln1s + l * 1024,
                                                  enc_ln1b + l * 1024);
        GEMM(OM_BF16, Rln, WP_ENC_QKV + (size_t)l * 3145728, RqkvB, nullptr, 3136, 3072, 1024);
        attn_kernel<49, 16><<<64 * 16, 256, 0, stream>>>(RqkvB, Rhid);
        GEMM(OM_ACC, Rhid, WP_ENC_WO + (size_t)l * 1048576, Rx, nullptr, 3136, 1024, 1024);
        ln_kernel<1024><<<3136, 256, 0, stream>>>(Rx, Rln, enc_ln2s + l * 1024,
                                                  enc_ln2b + l * 1024);
        GEMM(OM_GELU, Rln, WP_ENC_W1 + (size_t)l * 4194304, Rhid, enc_b1 + l * 4096, 3136,
             4096, 1024);
        GEMM(OM_ACC, Rhid, WP_ENC_W2 + (size_t)l * 4194304, Rx, enc_b2 + l * 1024, 3136, 1024,
             4096);
    }
    ln_kernel<1024><<<3136, 256, 0, stream>>>(Rx, Rln, enc_lnfs, enc_lnfb);

    // 4) e2d -> dec_tok (f32, in QKV region), scatter into decoder residual (f32)
    GEMM(OM_F32, Rln, WP_E2D, RqkvF, e2d_b, 3136, 512, 1024);
    scatter_tokens<<<12544, 256, 0, stream>>>(RqkvF, dec_pos, mask_tok, ord, Rx);

    // 5) decoder
    ln_kernel<512><<<12544, 256, 0, stream>>>(Rx, Rln, dec_ln1s, dec_ln1b);
    GEMM(OM_BF16, Rln, WP_DEC_QKV, RqkvB, nullptr, 12544, 1536, 512);
    attn_kernel<196, 8><<<64 * 8, 256, 0, stream>>>(RqkvB, Rhid);
    GEMM(OM_ACC, Rhid, WP_DEC_WO, Rx, nullptr, 12544, 512, 512);
    ln_kernel<512><<<12544, 256, 0, stream>>>(Rx, Rln, dec_ln2s, dec_ln2b);
    GEMM(OM_GELU, Rln, WP_DEC_W1, Rhid, dec_b1, 12544, 2048, 512);
    GEMM(OM_ACC, Rhid, WP_DEC_W2, Rx, dec_b2, 12544, 512, 2048);
    ln_kernel<512><<<12544, 256, 0, stream>>>(Rx, Rln, dec_lnfs, dec_lnfb);

    // 6) gather masked, pix head (pred f32 in QKV region), MSE
    gather_masked<<<9408, 256, 0, stream>>>(Rln, ord, Rhid);
    GEMM(OM_F32, Rhid, WP_PIX, RqkvF, pix_b, 9408, 1024, 512);
    loss_partial<<<4096, 256, 0, stream>>>(RqkvF, patches, ord, part);
    loss_final<<<1, 256, 0, stream>>>(part, out);
}

// Round 3
// 1184.243 us; speedup vs baseline: 5.0661x; 2.1700x over previous
//
#include <hip/hip_runtime.h>

typedef __attribute__((ext_vector_type(8))) __bf16 bf16x8;
typedef __attribute__((ext_vector_type(4))) float f32x4;

// ---------------- workspace layout (byte offsets) ----------------
#define OFF_PATCH 0ull          // bf16 12544x1024
#define OFF_X     25690112ull   // f32  max(3200x1024, 12544x512)
#define OFF_LN    51380224ull   // bf16 max(3200x1024, 12544x512)
#define OFF_QKV   64225280ull   // bf16 qkv / f32 dec_tok / f32 pred
#define OFF_HID   103022592ull  // bf16 max(12544x2048)
#define OFF_WP    154402816ull  // bf16 packed transposed weights
#define OFF_ORD   214695936ull  // int 12544
#define OFF_PART  214746112ull  // f32 4096

// bf16-element offsets inside packed-weight region
#define WP_PATCH   0ull
#define WP_ENC_QKV 786432ull
#define WP_ENC_WO  7077888ull
#define WP_ENC_W1  9175040ull
#define WP_ENC_W2  17563648ull
#define WP_E2D     25952256ull
#define WP_DEC_QKV 26476544ull
#define WP_DEC_WO  27262976ull
#define WP_DEC_W1  27525120ull
#define WP_DEC_W2  28573696ull
#define WP_PIX     29622272ull

#define OM_BF16 0
#define OM_F32  1
#define OM_ACC  2
#define OM_GELU 3

__device__ __forceinline__ float b2f(unsigned short u) {
    return __uint_as_float(((unsigned int)u) << 16);
}
__device__ __forceinline__ unsigned short f2b(float f) {
    unsigned int x = __float_as_uint(f);
    x += 0x7fffu + ((x >> 16) & 1u);
    return (unsigned short)(x >> 16);
}
__device__ __forceinline__ float gelu_f(float x) {
    float x3 = x * x * x;
    float t = tanhf(0.7978845608028654f * (x + 0.044715f * x3));
    return 0.5f * x * (1.0f + t);
}
__device__ __forceinline__ void gload16(const void* g, void* l) {
    __builtin_amdgcn_global_load_lds((const __attribute__((address_space(1))) void*)g,
                                     (__attribute__((address_space(3))) void*)l, 16, 0, 0);
}

// ---------------- weight pack: W[K][N] f32 -> Wt[N][K] bf16 ----------------
__global__ __launch_bounds__(256) void pack_w(const float* __restrict__ in,
                                              unsigned short* __restrict__ out, int K, int N) {
    __shared__ float tile[32][33];
    int kt = blockIdx.y * 32, nt = blockIdx.x * 32;
    int tx = threadIdx.x & 31, ty = threadIdx.x >> 5;  // 32 x 8
#pragma unroll
    for (int i = 0; i < 32; i += 8) tile[ty + i][tx] = in[(size_t)(kt + ty + i) * N + nt + tx];
    __syncthreads();
#pragma unroll
    for (int i = 0; i < 32; i += 8)
        out[(size_t)(nt + ty + i) * K + kt + tx] = f2b(tile[tx][ty + i]);
}

// ---------------- patchify: images -> Xp bf16 [12544][768] ----------------
__global__ __launch_bounds__(256) void patchify_kernel(const float* __restrict__ img,
                                                       unsigned short* __restrict__ Xp) {
    const long long total = 12544ll * 768;
    for (long long e = (long long)blockIdx.x * 256 + threadIdx.x; e < total;
         e += (long long)gridDim.x * 256) {
        int row = (int)(e / 768), k = (int)(e % 768);
        int b = row / 196, pi = row % 196;
        int py = pi / 14, px = pi % 14;
        int r = k / 48, rem = k % 48;
        int c = rem / 3, ch = rem % 3;
        long long src = (((long long)(b * 224 + py * 16 + r)) * 224 + (px * 16 + c)) * 3 + ch;
        Xp[e] = f2b(img[src]);
    }
}

// ---------------- MFMA GEMM: C[MxN] = A[MxK](bf16) @ Bt[NxK](bf16)^T ----------------
// 128x128 tile, BK=64, 4 waves; staging via global_load_lds width=16 (m97 structure).
template <int OM>
__global__ __launch_bounds__(256) void gemm_mfma(const unsigned short* __restrict__ A,
                                                 const unsigned short* __restrict__ Bt,
                                                 void* __restrict__ Cv,
                                                 const float* __restrict__ bias,
                                                 int M, int N, int K) {
    __shared__ __align__(16) unsigned short As[128 * 64];
    __shared__ __align__(16) unsigned short Bs[128 * 64];
    const int tid = threadIdx.x;
    const int wave = tid >> 6, lane = tid & 63;
    const int brow = blockIdx.y * 128, bcol = blockIdx.x * 128;
    const int fr = lane & 15, fq = lane >> 4;
    const int wr = (wave >> 1) * 64, wc = (wave & 1) * 64;
    // staging: each wave fills rows [wave*32, wave*32+32) of As/Bs; one instr = 8 rows
    const int srow = wave * 32 + (lane >> 3);
    const int scol = (lane & 7) * 8;
    const unsigned short* Ag = A + (size_t)(brow + srow) * K + scol;
    const unsigned short* Bg = Bt + (size_t)(bcol + srow) * K + scol;
    unsigned short* AsW = As + (wave * 32) * 64;
    unsigned short* BsW = Bs + (wave * 32) * 64;
    f32x4 acc[4][4];
#pragma unroll
    for (int m = 0; m < 4; ++m)
#pragma unroll
        for (int n = 0; n < 4; ++n) acc[m][n] = (f32x4){0.f, 0.f, 0.f, 0.f};

    for (int k0 = 0; k0 < K; k0 += 64) {
        __syncthreads();  // previous compute done before overwrite
#pragma unroll
        for (int i = 0; i < 4; ++i) {
            gload16(Ag + (size_t)(i * 8) * K + k0, AsW + i * 8 * 64);
            gload16(Bg + (size_t)(i * 8) * K + k0, BsW + i * 8 * 64);
        }
        __syncthreads();  // drains vmcnt(0): staged data visible
#pragma unroll
        for (int kk = 0; kk < 2; ++kk) {
            bf16x8 af[4], bfr[4];
#pragma unroll
            for (int m = 0; m < 4; ++m)
                af[m] = *(const bf16x8*)&As[(wr + m * 16 + fr) * 64 + kk * 32 + fq * 8];
#pragma unroll
            for (int n = 0; n < 4; ++n)
                bfr[n] = *(const bf16x8*)&Bs[(wc + n * 16 + fr) * 64 + kk * 32 + fq * 8];
#pragma unroll
            for (int m = 0; m < 4; ++m)
#pragma unroll
                for (int n = 0; n < 4; ++n)
                    acc[m][n] = __builtin_amdgcn_mfma_f32_16x16x32_bf16(af[m], bfr[n],
                                                                       acc[m][n], 0, 0, 0);
        }
    }
#pragma unroll
    for (int m = 0; m < 4; ++m) {
        int rbase = brow + wr + m * 16 + fq * 4;
#pragma unroll
        for (int r = 0; r < 4; ++r) {
            int row = rbase + r;
            if (row < M) {
#pragma unroll
                for (int n = 0; n < 4; ++n) {
                    int col = bcol + wc + n * 16 + fr;
                    float v = acc[m][n][r];
                    if (bias) v += bias[col];
                    size_t o = (size_t)row * N + col;
                    if constexpr (OM == OM_BF16) ((unsigned short*)Cv)[o] = f2b(v);
                    else if constexpr (OM == OM_F32) ((float*)Cv)[o] = v;
                    else if constexpr (OM == OM_ACC) ((float*)Cv)[o] += v;
                    else ((unsigned short*)Cv)[o] = f2b(gelu_f(v));
                }
            }
        }
    }
}

// ---------------- MFMA attention: one block per (b,h) ----------------
// K in LDS (XOR-swizzled rows), V transposed in LDS, P via per-wave LDS.
template <int N, int H, int NW>
__global__ __launch_bounds__(NW * 64) void attn_mfma(const unsigned short* __restrict__ qkv,
                                                     unsigned short* __restrict__ out) {
    constexpr int Npad = ((N + 31) / 32) * 32;
    constexpr int NT = Npad / 16;
    constexpr int KS = Npad / 32;
    constexpr int PS = Npad + 8;  // elem stride; *2 bytes = odd multiple of 16B -> bank-spread
    constexpr int SQ = 3 * H * 64, SO = H * 64;
    __shared__ __align__(16) unsigned short Kl[Npad * 64];
    __shared__ __align__(16) unsigned short Vt[64 * PS];
    __shared__ __align__(16) unsigned short Pl[NW * 16 * PS];
    const int b = blockIdx.x / H, h = blockIdx.x % H;
    const unsigned short* base = qkv + (size_t)b * N * SQ;
    const int qoff = h * 64, koff = (H + h) * 64, voff = (2 * H + h) * 64;
    const int tid = threadIdx.x, wave = tid >> 6, lane = tid & 63;
    const int fr = lane & 15, fq = lane >> 4;

    // stage K rows (zero-filled padding), XOR swizzle on 16B chunks
    for (int idx = tid; idx < Npad * 8; idx += NW * 64) {
        int row = idx >> 3, ch = idx & 7;
        uint4 v = {0u, 0u, 0u, 0u};
        if (row < N) v = *(const uint4*)(base + (size_t)row * SQ + koff + ch * 8);
        *(uint4*)((char*)Kl + row * 128 + ((ch * 16) ^ ((row & 7) << 4))) = v;
    }
    // stage V transposed: Vt[d][key]
    for (int idx = tid; idx < Npad * 32; idx += NW * 64) {
        int key = idx >> 5, d2 = (idx & 31) * 2;
        unsigned int v = 0;
        if (key < N) v = *(const unsigned int*)(base + (size_t)key * SQ + voff + d2);
        Vt[d2 * PS + key] = (unsigned short)(v & 0xffffu);
        Vt[(d2 + 1) * PS + key] = (unsigned short)(v >> 16);
    }
    __syncthreads();

    unsigned short* pw = Pl + wave * 16 * PS;
    for (int qt = wave; qt < NT; qt += NW) {
        const int q0 = qt * 16;
        int qr = q0 + fr;
        if (qr > N - 1) qr = N - 1;
        const unsigned short* qp = base + (size_t)qr * SQ + qoff + fq * 8;
        bf16x8 aq0 = *(const bf16x8*)qp;
        bf16x8 aq1 = *(const bf16x8*)(qp + 32);
        f32x4 sa[NT];
#pragma unroll
        for (int ct = 0; ct < NT; ++ct) sa[ct] = (f32x4){0.f, 0.f, 0.f, 0.f};
#pragma unroll
        for (int ct = 0; ct < NT; ++ct) {
            const char* kb = (const char*)Kl + (ct * 16 + fr) * 128;
            bf16x8 kf0 = *(const bf16x8*)(kb + ((fq * 16) ^ ((fr & 7) << 4)));
            bf16x8 kf1 = *(const bf16x8*)(kb + ((64 + fq * 16) ^ ((fr & 7) << 4)));
            sa[ct] = __builtin_amdgcn_mfma_f32_16x16x32_bf16(aq0, kf0, sa[ct], 0, 0, 0);
            sa[ct] = __builtin_amdgcn_mfma_f32_16x16x32_bf16(aq1, kf1, sa[ct], 0, 0, 0);
        }
        // row softmax: rows q0 + fq*4 + r; cols spread over fr-lanes and ct
        float mrow[4] = {-3e38f, -3e38f, -3e38f, -3e38f};
#pragma unroll
        for (int ct = 0; ct < NT; ++ct) {
            bool ok = (ct * 16 + fr) < N;
#pragma unroll
            for (int r = 0; r < 4; ++r) {
                float s = ok ? sa[ct][r] * 0.125f : -3e38f;
                sa[ct][r] = s;
                mrow[r] = fmaxf(mrow[r], s);
            }
        }
#pragma unroll
        for (int off = 1; off <= 8; off <<= 1)
#pragma unroll
            for (int r = 0; r < 4; ++r) mrow[r] = fmaxf(mrow[r], __shfl_xor(mrow[r], off));
        float ssum[4] = {0.f, 0.f, 0.f, 0.f};
#pragma unroll
        for (int ct = 0; ct < NT; ++ct)
#pragma unroll
            for (int r = 0; r < 4; ++r) {
                float p = __expf(sa[ct][r] - mrow[r]);
                sa[ct][r] = p;
                ssum[r] += p;
            }
#pragma unroll
        for (int off = 1; off <= 8; off <<= 1)
#pragma unroll
            for (int r = 0; r < 4; ++r) ssum[r] += __shfl_xor(ssum[r], off);
        // write unnormalized P (bf16) to per-wave LDS
#pragma unroll
        for (int ct = 0; ct < NT; ++ct)
#pragma unroll
            for (int r = 0; r < 4; ++r)
                pw[(fq * 4 + r) * PS + ct * 16 + fr] = f2b(sa[ct][r]);
        // O = P @ V
        f32x4 oa[4];
#pragma unroll
        for (int vt = 0; vt < 4; ++vt) oa[vt] = (f32x4){0.f, 0.f, 0.f, 0.f};
#pragma unroll
        for (int ks = 0; ks < KS; ++ks) {
            bf16x8 pa = *(const bf16x8*)(pw + fr * PS + ks * 32 + fq * 8);
#pragma unroll
            for (int vt = 0; vt < 4; ++vt) {
                bf16x8 vf = *(const bf16x8*)(&Vt[(vt * 16 + fr) * PS + ks * 32 + fq * 8]);
                oa[vt] = __builtin_amdgcn_mfma_f32_16x16x32_bf16(pa, vf, oa[vt], 0, 0, 0);
            }
        }
        float inv[4];
#pragma unroll
        for (int r = 0; r < 4; ++r) inv[r] = 1.f / ssum[r];
#pragma unroll
        for (int vt = 0; vt < 4; ++vt)
#pragma unroll
            for (int r = 0; r < 4; ++r) {
                int q = q0 + fq * 4 + r;
                if (q < N)
                    out[((size_t)b * N + q) * SO + h * 64 + vt * 16 + fr] =
                        f2b(oa[vt][r] * inv[r]);
            }
    }
}

// ---------------- stable argsort of 196 per batch ----------------
__global__ __launch_bounds__(256) void argsort_kernel(const float* __restrict__ rnd,
                                                      int* __restrict__ ord) {
    __shared__ float vals[196];
    int b = blockIdx.x, t = threadIdx.x;
    if (t < 196) vals[t] = rnd[b * 196 + t];
    __syncthreads();
    if (t < 196) {
        float v = vals[t];
        int rank = 0;
        for (int j = 0; j < 196; ++j) {
            float vj = vals[j];
            rank += (vj < v) || (vj == v && j < t);
        }
        ord[b * 196 + rank] = t;
    }
}

__global__ __launch_bounds__(256) void gather_unmasked(const unsigned short* __restrict__ patches,
                                                       const float* __restrict__ pos,
                                                       const int* __restrict__ ord,
                                                       float* __restrict__ xe) {
    int row = blockIdx.x;  // 0..3135
    int b = row / 49, i = row % 49;
    int src = ord[b * 196 + 147 + i];
    const unsigned short* pr = patches + ((size_t)(b * 196 + src) << 10);
    const float* pe = pos + ((size_t)src << 10);
    float* o = xe + ((size_t)row << 10);
    int d = threadIdx.x * 4;
    ushort4 pv = *(const ushort4*)(pr + d);
    float4 p4 = *(const float4*)(pe + d);
    float4 r;
    r.x = b2f(pv.x) + p4.x; r.y = b2f(pv.y) + p4.y;
    r.z = b2f(pv.z) + p4.z; r.w = b2f(pv.w) + p4.w;
    *(float4*)(o + d) = r;
}

// ---------------- LayerNorm: f32 in -> bf16 out ----------------
template <int L>
__global__ __launch_bounds__(256) void ln_kernel(const float* __restrict__ x,
                                                 unsigned short* __restrict__ y,
                                                 const float* __restrict__ sw,
                                                 const float* __restrict__ bw) {
    __shared__ float red[8];
    const int tid = threadIdx.x;
    const float* xr = x + (size_t)blockIdx.x * L;
    float sum = 0.f, sq = 0.f;
    for (int i = tid * 4; i < L; i += 1024) {
        float4 v = *(const float4*)(xr + i);
        sum += v.x + v.y + v.z + v.w;
        sq += v.x * v.x + v.y * v.y + v.z * v.z + v.w * v.w;
    }
    for (int off = 32; off; off >>= 1) {
        sum += __shfl_xor(sum, off);
        sq += __shfl_xor(sq, off);
    }
    int wave = tid >> 6, lane = tid & 63;
    if (lane == 0) { red[wave] = sum; red[4 + wave] = sq; }
    __syncthreads();
    float ts = red[0] + red[1] + red[2] + red[3];
    float tq = red[4] + red[5] + red[6] + red[7];
    float mean = ts / L;
    float inv = rsqrtf(tq / L - mean * mean + 1e-5f);
    unsigned short* yr = y + (size_t)blockIdx.x * L;
    for (int i = tid * 4; i < L; i += 1024) {
        float4 v = *(const float4*)(xr + i);
        float4 s4 = *(const float4*)(sw + i);
        float4 b4 = *(const float4*)(bw + i);
        ushort4 o;
        o.x = f2b((v.x - mean) * inv * s4.x + b4.x);
        o.y = f2b((v.y - mean) * inv * s4.y + b4.y);
        o.z = f2b((v.z - mean) * inv * s4.z + b4.z);
        o.w = f2b((v.w - mean) * inv * s4.w + b4.w);
        *(ushort4*)(yr + i) = o;
    }
}

__global__ __launch_bounds__(256) void scatter_tokens(const float* __restrict__ dec_tok,
                                                      const float* __restrict__ dec_pos,
                                                      const float* __restrict__ mask_tok,
                                                      const int* __restrict__ ord,
                                                      float* __restrict__ all_tok) {
    int e = blockIdx.x;  // 0..12543
    int b = e / 196, i = e % 196;
    int idx = ord[e];
    float* o = all_tok + ((size_t)(b * 196 + idx)) * 512;
    const float* dp = dec_pos + (size_t)idx * 512;
    int d = threadIdx.x * 4;
    if (d < 512) {
        float4 dv = *(const float4*)(dp + d);
        float4 sv;
        if (i < 147) sv = *(const float4*)(mask_tok + d);
        else sv = *(const float4*)(dec_tok + ((size_t)(b * 49 + (i - 147))) * 512 + d);
        float4 r = {sv.x + dv.x, sv.y + dv.y, sv.z + dv.z, sv.w + dv.w};
        *(float4*)(o + d) = r;
    }
}

__global__ __launch_bounds__(256) void gather_masked(const unsigned short* __restrict__ x,
                                                     const int* __restrict__ ord,
                                                     unsigned short* __restrict__ gm) {
    int r = blockIdx.x;  // 0..9407
    int b = r / 147, j = r % 147;
    int idx = ord[b * 196 + j];
    const unsigned short* src = x + ((size_t)(b * 196 + idx)) * 512;
    unsigned short* o = gm + (size_t)r * 512;
    int d = threadIdx.x * 4;
    if (d < 512) *(ushort4*)(o + d) = *(const ushort4*)(src + d);
}

__global__ __launch_bounds__(256) void loss_partial(const float* __restrict__ pred,
                                                    const unsigned short* __restrict__ patches,
                                                    const int* __restrict__ ord,
                                                    float* __restrict__ part) {
    __shared__ float red[8];
    float local = 0.f;
    const long long total = 9633792ll;  // 9408*1024
    for (long long e = (long long)blockIdx.x * 256 + threadIdx.x; e < total; e += 4096ll * 256) {
        int r = (int)(e >> 10), d = (int)(e & 1023);
        int b = r / 147, j = r % 147;
        int idx = ord[b * 196 + j];
        float t = b2f(patches[(((size_t)(b * 196 + idx)) << 10) + d]);
        float df = pred[e] - t;
        local += df * df;
    }
    for (int off = 32; off; off >>= 1) local += __shfl_xor(local, off);
    int wave = threadIdx.x >> 6, lane = threadIdx.x & 63;
    if (lane == 0) red[wave] = local;
    __syncthreads();
    if (threadIdx.x == 0) part[blockIdx.x] = red[0] + red[1] + red[2] + red[3];
}

__global__ __launch_bounds__(256) void loss_final(const float* __restrict__ part,
                                                  float* __restrict__ out) {
    __shared__ float red[8];
    float local = 0.f;
    for (int i = threadIdx.x; i < 4096; i += 256) local += part[i];
    for (int off = 32; off; off >>= 1) local += __shfl_xor(local, off);
    int wave = threadIdx.x >> 6, lane = threadIdx.x & 63;
    if (lane == 0) red[wave] = local;
    __syncthreads();
    if (threadIdx.x == 0) out[0] = (red[0] + red[1] + red[2] + red[3]) / 9633792.0f;
}

extern "C" void kernel_launch(void* const* d_in, const int* in_sizes, int n_in, void* d_out,
                              int out_size, void* d_ws, size_t ws_size, hipStream_t stream) {
    const float* images = (const float*)d_in[0];
    const float* rnd = (const float*)d_in[1];
    const float* patch_W = (const float*)d_in[2];
    const float* patch_b = (const float*)d_in[3];
    const float* pos_emb = (const float*)d_in[4];
    const float* enc_ln1s = (const float*)d_in[5];
    const float* enc_ln1b = (const float*)d_in[6];
    const float* enc_Wqkv = (const float*)d_in[7];
    const float* enc_Wo = (const float*)d_in[8];
    const float* enc_ln2s = (const float*)d_in[9];
    const float* enc_ln2b = (const float*)d_in[10];
    const float* enc_W1 = (const float*)d_in[11];
    const float* enc_b1 = (const float*)d_in[12];
    const float* enc_W2 = (const float*)d_in[13];
    const float* enc_b2 = (const float*)d_in[14];
    const float* enc_lnfs = (const float*)d_in[15];
    const float* enc_lnfb = (const float*)d_in[16];
    const float* e2d_W = (const float*)d_in[17];
    const float* e2d_b = (const float*)d_in[18];
    const float* mask_tok = (const float*)d_in[19];
    const float* dec_pos = (const float*)d_in[20];
    const float* dec_ln1s = (const float*)d_in[21];
    const float* dec_ln1b = (const float*)d_in[22];
    const float* dec_Wqkv = (const float*)d_in[23];
    const float* dec_Wo = (const float*)d_in[24];
    const float* dec_ln2s = (const float*)d_in[25];
    const float* dec_ln2b = (const float*)d_in[26];
    const float* dec_W1 = (const float*)d_in[27];
    const float* dec_b1 = (const float*)d_in[28];
    const float* dec_W2 = (const float*)d_in[29];
    const float* dec_b2 = (const float*)d_in[30];
    const float* dec_lnfs = (const float*)d_in[31];
    const float* dec_lnfb = (const float*)d_in[32];
    const float* pix_W = (const float*)d_in[33];
    const float* pix_b = (const float*)d_in[34];

    char* ws = (char*)d_ws;
    unsigned short* patches = (unsigned short*)(ws + OFF_PATCH);
    float* Rx = (float*)(ws + OFF_X);
    unsigned short* Rln = (unsigned short*)(ws + OFF_LN);
    unsigned short* RqkvB = (unsigned short*)(ws + OFF_QKV);
    float* RqkvF = (float*)(ws + OFF_QKV);
    unsigned short* Rhid = (unsigned short*)(ws + OFF_HID);
    unsigned short* wp = (unsigned short*)(ws + OFF_WP);
    int* ord = (int*)(ws + OFF_ORD);
    float* part = (float*)(ws + OFF_PART);
    float* out = (float*)d_out;

    // ---- pack all weights: [K][N] f32 -> [N][K] bf16 ----
    auto PACK = [&](const float* src, size_t wpo, int K, int N) {
        pack_w<<<dim3(N / 32, K / 32), 256, 0, stream>>>(src, wp + wpo, K, N);
    };
    PACK(patch_W, WP_PATCH, 768, 1024);
    for (int l = 0; l < 2; ++l) {
        PACK(enc_Wqkv + (size_t)l * 1024 * 3072, WP_ENC_QKV + (size_t)l * 3145728, 1024, 3072);
        PACK(enc_Wo + (size_t)l * 1024 * 1024, WP_ENC_WO + (size_t)l * 1048576, 1024, 1024);
        PACK(enc_W1 + (size_t)l * 1024 * 4096, WP_ENC_W1 + (size_t)l * 4194304, 1024, 4096);
        PACK(enc_W2 + (size_t)l * 4096 * 1024, WP_ENC_W2 + (size_t)l * 4194304, 4096, 1024);
    }
    PACK(e2d_W, WP_E2D, 1024, 512);
    PACK(dec_Wqkv, WP_DEC_QKV, 512, 1536);
    PACK(dec_Wo, WP_DEC_WO, 512, 512);
    PACK(dec_W1, WP_DEC_W1, 512, 2048);
    PACK(dec_W2, WP_DEC_W2, 2048, 512);
    PACK(pix_W, WP_PIX, 512, 1024);

    auto GEMM = [&](int om, const unsigned short* A, size_t wpo, void* C, const float* bias,
                    int M, int N, int K) {
        dim3 g(N / 128, (M + 127) / 128);
        const unsigned short* Bt = wp + wpo;
        if (om == OM_BF16) gemm_mfma<OM_BF16><<<g, 256, 0, stream>>>(A, Bt, C, bias, M, N, K);
        else if (om == OM_F32) gemm_mfma<OM_F32><<<g, 256, 0, stream>>>(A, Bt, C, bias, M, N, K);
        else if (om == OM_ACC) gemm_mfma<OM_ACC><<<g, 256, 0, stream>>>(A, Bt, C, bias, M, N, K);
        else gemm_mfma<OM_GELU><<<g, 256, 0, stream>>>(A, Bt, C, bias, M, N, K);
    };

    // 1) patchify (Xp bf16 in Rhid), patches = Xp @ patch_W + b  (bf16)
    patchify_kernel<<<4096, 256, 0, stream>>>(images, Rhid);
    GEMM(OM_BF16, Rhid, WP_PATCH, patches, patch_b, 12544, 1024, 768);
    // 2) argsort + gather unmasked (fp32 residual stream)
    argsort_kernel<<<64, 256, 0, stream>>>(rnd, ord);
    gather_unmasked<<<3136, 256, 0, stream>>>(patches, pos_emb, ord, Rx);

    // 3) encoder
    for (int l = 0; l < 2; ++l) {
        ln_kernel<1024><<<3136, 256, 0, stream>>>(Rx, Rln, enc_ln1s + l * 1024,
                                                  enc_ln1b + l * 1024);
        GEMM(OM_BF16, Rln, WP_ENC_QKV + (size_t)l * 3145728, RqkvB, nullptr, 3136, 3072, 1024);
        attn_mfma<49, 16, 4><<<64 * 16, 256, 0, stream>>>(RqkvB, Rhid);
        GEMM(OM_ACC, Rhid, WP_ENC_WO + (size_t)l * 1048576, Rx, nullptr, 3136, 1024, 1024);
        ln_kernel<1024><<<3136, 256, 0, stream>>>(Rx, Rln, enc_ln2s + l * 1024,
                                                  enc_ln2b + l * 1024);
        GEMM(OM_GELU, Rln, WP_ENC_W1 + (size_t)l * 4194304, Rhid, enc_b1 + l * 4096, 3136,
             4096, 1024);
        GEMM(OM_ACC, Rhid, WP_ENC_W2 + (size_t)l * 4194304, Rx, enc_b2 + l * 1024, 3136, 1024,
             4096);
    }
    ln_kernel<1024><<<3136, 256, 0, stream>>>(Rx, Rln, enc_lnfs, enc_lnfb);

    // 4) e2d -> dec_tok (f32, in QKV region), scatter into decoder residual (f32)
    GEMM(OM_F32, Rln, WP_E2D, RqkvF, e2d_b, 3136, 512, 1024);
    scatter_tokens<<<12544, 256, 0, stream>>>(RqkvF, dec_pos, mask_tok, ord, Rx);

    // 5) decoder
    ln_kernel<512><<<12544, 256, 0, stream>>>(Rx, Rln, dec_ln1s, dec_ln1b);
    GEMM(OM_BF16, Rln, WP_DEC_QKV, RqkvB, nullptr, 12544, 1536, 512);
    attn_mfma<196, 8, 8><<<64 * 8, 512, 0, stream>>>(RqkvB, Rhid);
    GEMM(OM_ACC, Rhid, WP_DEC_WO, Rx, nullptr, 12544, 512, 512);
    ln_kernel<512><<<12544, 256, 0, stream>>>(Rx, Rln, dec_ln2s, dec_ln2b);
    GEMM(OM_GELU, Rln, WP_DEC_W1, Rhid, dec_b1, 12544, 2048, 512);
    GEMM(OM_ACC, Rhid, WP_DEC_W2, Rx, dec_b2, 12544, 512, 2048);
    ln_kernel<512><<<12544, 256, 0, stream>>>(Rx, Rln, dec_lnfs, dec_lnfb);

    // 6) gather masked, pix head (pred f32 in QKV region), MSE
    gather_masked<<<9408, 256, 0, stream>>>(Rln, ord, Rhid);
    GEMM(OM_F32, Rhid, WP_PIX, RqkvF, pix_b, 9408, 1024, 512);
    loss_partial<<<4096, 256, 0, stream>>>(RqkvF, patches, ord, part);
    loss_final<<<1, 256, 0, stream>>>(part, out);
}

// Round 4
// 1052.109 us; speedup vs baseline: 5.7024x; 1.1256x over previous
//
#include <hip/hip_runtime.h>

typedef __attribute__((ext_vector_type(8))) __bf16 bf16x8;
typedef __attribute__((ext_vector_type(4))) float f32x4;

// ---------------- workspace layout (byte offsets) ----------------
#define OFF_PATCH 0ull          // bf16 12544x1024
#define OFF_X     25690112ull   // f32  max(3200x1024, 12544x512)
#define OFF_LN    51380224ull   // bf16 max(3200x1024, 12544x512)
#define OFF_QKV   64225280ull   // bf16 qkv / f32 dec_tok / f32 pred
#define OFF_HID   103022592ull  // bf16 max(12544x2048)
#define OFF_WP    154402816ull  // bf16 packed transposed weights
#define OFF_ORD   214695936ull  // int 12544
#define OFF_PART  214746112ull  // f32 4096

// bf16-element offsets inside packed-weight region
#define WP_PATCH   0ull
#define WP_ENC_QKV 786432ull
#define WP_ENC_WO  7077888ull
#define WP_ENC_W1  9175040ull
#define WP_ENC_W2  17563648ull
#define WP_E2D     25952256ull
#define WP_DEC_QKV 26476544ull
#define WP_DEC_WO  27262976ull
#define WP_DEC_W1  27525120ull
#define WP_DEC_W2  28573696ull
#define WP_PIX     29622272ull

#define OM_BF16 0
#define OM_F32  1
#define OM_ACC  2
#define OM_GELU 3

__device__ __forceinline__ float b2f(unsigned short u) {
    return __uint_as_float(((unsigned int)u) << 16);
}
__device__ __forceinline__ unsigned short f2b(float f) {
    unsigned int x = __float_as_uint(f);
    x += 0x7fffu + ((x >> 16) & 1u);
    return (unsigned short)(x >> 16);
}
// gelu(x) = 0.5x(1+tanh(u)) = x * sigmoid(2u), u = 0.79788456(x + 0.044715 x^3)
__device__ __forceinline__ float gelu_f(float x) {
    float u2 = 1.5957691216057308f * x * (1.f + 0.044715f * x * x);
    return x / (1.f + __expf(-u2));
}
__device__ __forceinline__ void gload16(const void* g, void* l) {
    __builtin_amdgcn_global_load_lds((const __attribute__((address_space(1))) void*)g,
                                     (__attribute__((address_space(3))) void*)l, 16, 0, 0);
}

// ---------------- weight pack: W[K][N] f32 -> Wt[N][K] bf16 ----------------
__global__ __launch_bounds__(256) void pack_w(const float* __restrict__ in,
                                              unsigned short* __restrict__ out, int K, int N) {
    __shared__ float tile[32][33];
    int kt = blockIdx.y * 32, nt = blockIdx.x * 32;
    int tx = threadIdx.x & 31, ty = threadIdx.x >> 5;  // 32 x 8
#pragma unroll
    for (int i = 0; i < 32; i += 8) tile[ty + i][tx] = in[(size_t)(kt + ty + i) * N + nt + tx];
    __syncthreads();
#pragma unroll
    for (int i = 0; i < 32; i += 8)
        out[(size_t)(nt + ty + i) * K + kt + tx] = f2b(tile[tx][ty + i]);
}

// ---------------- patchify: images -> Xp bf16 [12544][768] ----------------
__global__ __launch_bounds__(256) void patchify_kernel(const float* __restrict__ img,
                                                       unsigned short* __restrict__ Xp) {
    const long long total = 12544ll * 768;
    for (long long e = (long long)blockIdx.x * 256 + threadIdx.x; e < total;
         e += (long long)gridDim.x * 256) {
        int row = (int)(e / 768), k = (int)(e % 768);
        int b = row / 196, pi = row % 196;
        int py = pi / 14, px = pi % 14;
        int r = k / 48, rem = k % 48;
        int c = rem / 3, ch = rem % 3;
        long long src = (((long long)(b * 224 + py * 16 + r)) * 224 + (px * 16 + c)) * 3 + ch;
        Xp[e] = f2b(img[src]);
    }
}

// ---------------- MFMA GEMM, 2-phase double-buffered, XOR-swizzled LDS ----------------
// C[MxN] = A[MxK](bf16) @ Bt[NxK](bf16)^T.  BT x BT tile, BK=64.
// BT=256: 8 waves (2x4), MR=8. BT=128: 4 waves (2x2), MR=4. NR=4 both.
// Schedule per K-step: STAGE(next buf) -> ds_read+MFMA(cur) -> syncthreads (drains vmcnt).
template <int BT, int NW, int OM>
__global__ __launch_bounds__(NW * 64) void gemm2(const unsigned short* __restrict__ A,
                                                 const unsigned short* __restrict__ Bt,
                                                 void* __restrict__ Cv,
                                                 const float* __restrict__ bias,
                                                 int M, int N, int K) {
    constexpr int WN = (BT == 256) ? 4 : 2;
    constexpr int MR = BT / 32;
    __shared__ __align__(16) unsigned short As[2][BT * 64];
    __shared__ __align__(16) unsigned short Bs[2][BT * 64];
    const int tid = threadIdx.x, wave = tid >> 6, lane = tid & 63;
    const int brow = blockIdx.y * BT, bcol = blockIdx.x * BT;
    const int fr = lane & 15, fq = lane >> 4;
    const int wr = (wave / WN) * (MR * 16);
    const int wc = (wave % WN) * 64;
    // staging: wave covers tile rows [wave*32, wave*32+32). gload_lds dest is
    // wave-uniform base + lane*16; source chunk pre-swizzled so that LDS slot
    // (row, ch) holds global chunk ch^(row&7).
    const int srow = wave * 32 + (lane >> 3);
    const int sca = ((lane & 7) ^ (lane >> 3)) * 8;  // swizzled source col (elems)
    const unsigned short* Ag = A + (size_t)(brow + srow) * K + sca;
    const unsigned short* Bg = Bt + (size_t)(bcol + srow) * K + sca;

    f32x4 acc[MR][4];
#pragma unroll
    for (int m = 0; m < MR; ++m)
#pragma unroll
        for (int n = 0; n < 4; ++n) acc[m][n] = (f32x4){0.f, 0.f, 0.f, 0.f};

    auto stage = [&](int buf, int k0) {
        unsigned short* AsW = &As[buf][(wave * 32) * 64];
        unsigned short* BsW = &Bs[buf][(wave * 32) * 64];
#pragma unroll
        for (int i = 0; i < 4; ++i) {
            gload16(Ag + (size_t)(i * 8) * K + k0, AsW + i * 8 * 64);
            gload16(Bg + (size_t)(i * 8) * K + k0, BsW + i * 8 * 64);
        }
    };
    auto compute = [&](int buf) {
        const char* ab = (const char*)&As[buf][0];
        const char* bb = (const char*)&Bs[buf][0];
        const int sw = (fr & 7) << 4;
#pragma unroll
        for (int kk = 0; kk < 2; ++kk) {
            bf16x8 af[MR], bf[4];
#pragma unroll
            for (int m = 0; m < MR; ++m)
                af[m] = *(const bf16x8*)(ab + (wr + m * 16 + fr) * 128 +
                                         ((kk * 64 + fq * 16) ^ sw));
#pragma unroll
            for (int n = 0; n < 4; ++n)
                bf[n] = *(const bf16x8*)(bb + (wc + n * 16 + fr) * 128 +
                                         ((kk * 64 + fq * 16) ^ sw));
#pragma unroll
            for (int m = 0; m < MR; ++m)
#pragma unroll
                for (int n = 0; n < 4; ++n)
                    acc[m][n] = __builtin_amdgcn_mfma_f32_16x16x32_bf16(af[m], bf[n],
                                                                       acc[m][n], 0, 0, 0);
        }
    };

    const int nt = K >> 6;
    stage(0, 0);
    __syncthreads();
    int cur = 0;
    for (int t = 0; t < nt - 1; ++t) {
        stage(cur ^ 1, (t + 1) << 6);
        compute(cur);
        __syncthreads();
        cur ^= 1;
    }
    compute(cur);

#pragma unroll
    for (int m = 0; m < MR; ++m) {
        int rb = brow + wr + m * 16 + fq * 4;
#pragma unroll
        for (int r = 0; r < 4; ++r) {
            int row = rb + r;
            if (row < M) {
#pragma unroll
                for (int n = 0; n < 4; ++n) {
                    int col = bcol + wc + n * 16 + fr;
                    float v = acc[m][n][r];
                    if (bias) v += bias[col];
                    size_t o = (size_t)row * N + col;
                    if constexpr (OM == OM_BF16) ((unsigned short*)Cv)[o] = f2b(v);
                    else if constexpr (OM == OM_F32) ((float*)Cv)[o] = v;
                    else if constexpr (OM == OM_ACC) ((float*)Cv)[o] += v;
                    else ((unsigned short*)Cv)[o] = f2b(gelu_f(v));
                }
            }
        }
    }
}

// ---------------- MFMA attention: one block per (b,h) ----------------
template <int N, int H, int NW>
__global__ __launch_bounds__(NW * 64) void attn_mfma(const unsigned short* __restrict__ qkv,
                                                     unsigned short* __restrict__ out) {
    constexpr int Npad = ((N + 31) / 32) * 32;
    constexpr int NT = Npad / 16;
    constexpr int KS = Npad / 32;
    constexpr int PS = Npad + 8;
    constexpr int SQ = 3 * H * 64, SO = H * 64;
    __shared__ __align__(16) unsigned short Kl[Npad * 64];
    __shared__ __align__(16) unsigned short Vt[64 * PS];
    __shared__ __align__(16) unsigned short Pl[NW * 16 * PS];
    const int b = blockIdx.x / H, h = blockIdx.x % H;
    const unsigned short* base = qkv + (size_t)b * N * SQ;
    const int qoff = h * 64, koff = (H + h) * 64, voff = (2 * H + h) * 64;
    const int tid = threadIdx.x, wave = tid >> 6, lane = tid & 63;
    const int fr = lane & 15, fq = lane >> 4;

    for (int idx = tid; idx < Npad * 8; idx += NW * 64) {
        int row = idx >> 3, ch = idx & 7;
        uint4 v = {0u, 0u, 0u, 0u};
        if (row < N) v = *(const uint4*)(base + (size_t)row * SQ + koff + ch * 8);
        *(uint4*)((char*)Kl + row * 128 + ((ch * 16) ^ ((row & 7) << 4))) = v;
    }
    for (int idx = tid; idx < Npad * 32; idx += NW * 64) {
        int key = idx >> 5, d2 = (idx & 31) * 2;
        unsigned int v = 0;
        if (key < N) v = *(const unsigned int*)(base + (size_t)key * SQ + voff + d2);
        Vt[d2 * PS + key] = (unsigned short)(v & 0xffffu);
        Vt[(d2 + 1) * PS + key] = (unsigned short)(v >> 16);
    }
    __syncthreads();

    unsigned short* pw = Pl + wave * 16 * PS;
    for (int qt = wave; qt < NT; qt += NW) {
        const int q0 = qt * 16;
        int qr = q0 + fr;
        if (qr > N - 1) qr = N - 1;
        const unsigned short* qp = base + (size_t)qr * SQ + qoff + fq * 8;
        bf16x8 aq0 = *(const bf16x8*)qp;
        bf16x8 aq1 = *(const bf16x8*)(qp + 32);
        f32x4 sa[NT];
#pragma unroll
        for (int ct = 0; ct < NT; ++ct) sa[ct] = (f32x4){0.f, 0.f, 0.f, 0.f};
#pragma unroll
        for (int ct = 0; ct < NT; ++ct) {
            const char* kb = (const char*)Kl + (ct * 16 + fr) * 128;
            bf16x8 kf0 = *(const bf16x8*)(kb + ((fq * 16) ^ ((fr & 7) << 4)));
            bf16x8 kf1 = *(const bf16x8*)(kb + ((64 + fq * 16) ^ ((fr & 7) << 4)));
            sa[ct] = __builtin_amdgcn_mfma_f32_16x16x32_bf16(aq0, kf0, sa[ct], 0, 0, 0);
            sa[ct] = __builtin_amdgcn_mfma_f32_16x16x32_bf16(aq1, kf1, sa[ct], 0, 0, 0);
        }
        float mrow[4] = {-3e38f, -3e38f, -3e38f, -3e38f};
#pragma unroll
        for (int ct = 0; ct < NT; ++ct) {
            bool ok = (ct * 16 + fr) < N;
#pragma unroll
            for (int r = 0; r < 4; ++r) {
                float s = ok ? sa[ct][r] * 0.125f : -3e38f;
                sa[ct][r] = s;
                mrow[r] = fmaxf(mrow[r], s);
            }
        }
#pragma unroll
        for (int off = 1; off <= 8; off <<= 1)
#pragma unroll
            for (int r = 0; r < 4; ++r) mrow[r] = fmaxf(mrow[r], __shfl_xor(mrow[r], off));
        float ssum[4] = {0.f, 0.f, 0.f, 0.f};
#pragma unroll
        for (int ct = 0; ct < NT; ++ct)
#pragma unroll
            for (int r = 0; r < 4; ++r) {
                float p = __expf(sa[ct][r] - mrow[r]);
                sa[ct][r] = p;
                ssum[r] += p;
            }
#pragma unroll
        for (int off = 1; off <= 8; off <<= 1)
#pragma unroll
            for (int r = 0; r < 4; ++r) ssum[r] += __shfl_xor(ssum[r], off);
#pragma unroll
        for (int ct = 0; ct < NT; ++ct)
#pragma unroll
            for (int r = 0; r < 4; ++r)
                pw[(fq * 4 + r) * PS + ct * 16 + fr] = f2b(sa[ct][r]);
        f32x4 oa[4];
#pragma unroll
        for (int vt = 0; vt < 4; ++vt) oa[vt] = (f32x4){0.f, 0.f, 0.f, 0.f};
#pragma unroll
        for (int ks = 0; ks < KS; ++ks) {
            bf16x8 pa = *(const bf16x8*)(pw + fr * PS + ks * 32 + fq * 8);
#pragma unroll
            for (int vt = 0; vt < 4; ++vt) {
                bf16x8 vf = *(const bf16x8*)(&Vt[(vt * 16 + fr) * PS + ks * 32 + fq * 8]);
                oa[vt] = __builtin_amdgcn_mfma_f32_16x16x32_bf16(pa, vf, oa[vt], 0, 0, 0);
            }
        }
        float inv[4];
#pragma unroll
        for (int r = 0; r < 4; ++r) inv[r] = 1.f / ssum[r];
#pragma unroll
        for (int vt = 0; vt < 4; ++vt)
#pragma unroll
            for (int r = 0; r < 4; ++r) {
                int q = q0 + fq * 4 + r;
                if (q < N)
                    out[((size_t)b * N + q) * SO + h * 64 + vt * 16 + fr] =
                        f2b(oa[vt][r] * inv[r]);
            }
    }
}

// ---------------- stable argsort of 196 per batch ----------------
__global__ __launch_bounds__(256) void argsort_kernel(const float* __restrict__ rnd,
                                                      int* __restrict__ ord) {
    __shared__ float vals[196];
    int b = blockIdx.x, t = threadIdx.x;
    if (t < 196) vals[t] = rnd[b * 196 + t];
    __syncthreads();
    if (t < 196) {
        float v = vals[t];
        int rank = 0;
        for (int j = 0; j < 196; ++j) {
            float vj = vals[j];
            rank += (vj < v) || (vj == v && j < t);
        }
        ord[b * 196 + rank] = t;
    }
}

__global__ __launch_bounds__(256) void gather_unmasked(const unsigned short* __restrict__ patches,
                                                       const float* __restrict__ pos,
                                                       const int* __restrict__ ord,
                                                       float* __restrict__ xe) {
    int row = blockIdx.x;  // 0..3135
    int b = row / 49, i = row % 49;
    int src = ord[b * 196 + 147 + i];
    const unsigned short* pr = patches + ((size_t)(b * 196 + src) << 10);
    const float* pe = pos + ((size_t)src << 10);
    float* o = xe + ((size_t)row << 10);
    int d = threadIdx.x * 4;
    ushort4 pv = *(const ushort4*)(pr + d);
    float4 p4 = *(const float4*)(pe + d);
    float4 r;
    r.x = b2f(pv.x) + p4.x; r.y = b2f(pv.y) + p4.y;
    r.z = b2f(pv.z) + p4.z; r.w = b2f(pv.w) + p4.w;
    *(float4*)(o + d) = r;
}

// ---------------- LayerNorm: f32 in -> bf16 out ----------------
template <int L>
__global__ __launch_bounds__(256) void ln_kernel(const float* __restrict__ x,
                                                 unsigned short* __restrict__ y,
                                                 const float* __restrict__ sw,
                                                 const float* __restrict__ bw) {
    __shared__ float red[8];
    const int tid = threadIdx.x;
    const float* xr = x + (size_t)blockIdx.x * L;
    float sum = 0.f, sq = 0.f;
    for (int i = tid * 4; i < L; i += 1024) {
        float4 v = *(const float4*)(xr + i);
        sum += v.x + v.y + v.z + v.w;
        sq += v.x * v.x + v.y * v.y + v.z * v.z + v.w * v.w;
    }
    for (int off = 32; off; off >>= 1) {
        sum += __shfl_xor(sum, off);
        sq += __shfl_xor(sq, off);
    }
    int wave = tid >> 6, lane = tid & 63;
    if (lane == 0) { red[wave] = sum; red[4 + wave] = sq; }
    __syncthreads();
    float ts = red[0] + red[1] + red[2] + red[3];
    float tq = red[4] + red[5] + red[6] + red[7];
    float mean = ts / L;
    float inv = rsqrtf(tq / L - mean * mean + 1e-5f);
    unsigned short* yr = y + (size_t)blockIdx.x * L;
    for (int i = tid * 4; i < L; i += 1024) {
        float4 v = *(const float4*)(xr + i);
        float4 s4 = *(const float4*)(sw + i);
        float4 b4 = *(const float4*)(bw + i);
        ushort4 o;
        o.x = f2b((v.x - mean) * inv * s4.x + b4.x);
        o.y = f2b((v.y - mean) * inv * s4.y + b4.y);
        o.z = f2b((v.z - mean) * inv * s4.z + b4.z);
        o.w = f2b((v.w - mean) * inv * s4.w + b4.w);
        *(ushort4*)(yr + i) = o;
    }
}

__global__ __launch_bounds__(256) void scatter_tokens(const float* __restrict__ dec_tok,
                                                      const float* __restrict__ dec_pos,
                                                      const float* __restrict__ mask_tok,
                                                      const int* __restrict__ ord,
                                                      float* __restrict__ all_tok) {
    int e = blockIdx.x;  // 0..12543
    int b = e / 196, i = e % 196;
    int idx = ord[e];
    float* o = all_tok + ((size_t)(b * 196 + idx)) * 512;
    const float* dp = dec_pos + (size_t)idx * 512;
    int d = threadIdx.x * 4;
    if (d < 512) {
        float4 dv = *(const float4*)(dp + d);
        float4 sv;
        if (i < 147) sv = *(const float4*)(mask_tok + d);
        else sv = *(const float4*)(dec_tok + ((size_t)(b * 49 + (i - 147))) * 512 + d);
        float4 r = {sv.x + dv.x, sv.y + dv.y, sv.z + dv.z, sv.w + dv.w};
        *(float4*)(o + d) = r;
    }
}

__global__ __launch_bounds__(256) void gather_masked(const unsigned short* __restrict__ x,
                                                     const int* __restrict__ ord,
                                                     unsigned short* __restrict__ gm) {
    int r = blockIdx.x;  // 0..9407
    int b = r / 147, j = r % 147;
    int idx = ord[b * 196 + j];
    const unsigned short* src = x + ((size_t)(b * 196 + idx)) * 512;
    unsigned short* o = gm + (size_t)r * 512;
    int d = threadIdx.x * 4;
    if (d < 512) *(ushort4*)(o + d) = *(const ushort4*)(src + d);
}

__global__ __launch_bounds__(256) void loss_partial(const float* __restrict__ pred,
                                                    const unsigned short* __restrict__ patches,
                                                    const int* __restrict__ ord,
                                                    float* __restrict__ part) {
    __shared__ float red[8];
    float local = 0.f;
    const long long total = 9633792ll;  // 9408*1024
    for (long long e = (long long)blockIdx.x * 256 + threadIdx.x; e < total; e += 4096ll * 256) {
        int r = (int)(e >> 10), d = (int)(e & 1023);
        int b = r / 147, j = r % 147;
        int idx = ord[b * 196 + j];
        float t = b2f(patches[(((size_t)(b * 196 + idx)) << 10) + d]);
        float df = pred[e] - t;
        local += df * df;
    }
    for (int off = 32; off; off >>= 1) local += __shfl_xor(local, off);
    int wave = threadIdx.x >> 6, lane = threadIdx.x & 63;
    if (lane == 0) red[wave] = local;
    __syncthreads();
    if (threadIdx.x == 0) part[blockIdx.x] = red[0] + red[1] + red[2] + red[3];
}

__global__ __launch_bounds__(256) void loss_final(const float* __restrict__ part,
                                                  float* __restrict__ out) {
    __shared__ float red[8];
    float local = 0.f;
    for (int i = threadIdx.x; i < 4096; i += 256) local += part[i];
    for (int off = 32; off; off >>= 1) local += __shfl_xor(local, off);
    int wave = threadIdx.x >> 6, lane = threadIdx.x & 63;
    if (lane == 0) red[wave] = local;
    __syncthreads();
    if (threadIdx.x == 0) out[0] = (red[0] + red[1] + red[2] + red[3]) / 9633792.0f;
}

extern "C" void kernel_launch(void* const* d_in, const int* in_sizes, int n_in, void* d_out,
                              int out_size, void* d_ws, size_t ws_size, hipStream_t stream) {
    const float* images = (const float*)d_in[0];
    const float* rnd = (const float*)d_in[1];
    const float* patch_W = (const float*)d_in[2];
    const float* patch_b = (const float*)d_in[3];
    const float* pos_emb = (const float*)d_in[4];
    const float* enc_ln1s = (const float*)d_in[5];
    const float* enc_ln1b = (const float*)d_in[6];
    const float* enc_Wqkv = (const float*)d_in[7];
    const float* enc_Wo = (const float*)d_in[8];
    const float* enc_ln2s = (const float*)d_in[9];
    const float* enc_ln2b = (const float*)d_in[10];
    const float* enc_W1 = (const float*)d_in[11];
    const float* enc_b1 = (const float*)d_in[12];
    const float* enc_W2 = (const float*)d_in[13];
    const float* enc_b2 = (const float*)d_in[14];
    const float* enc_lnfs = (const float*)d_in[15];
    const float* enc_lnfb = (const float*)d_in[16];
    const float* e2d_W = (const float*)d_in[17];
    const float* e2d_b = (const float*)d_in[18];
    const float* mask_tok = (const float*)d_in[19];
    const float* dec_pos = (const float*)d_in[20];
    const float* dec_ln1s = (const float*)d_in[21];
    const float* dec_ln1b = (const float*)d_in[22];
    const float* dec_Wqkv = (const float*)d_in[23];
    const float* dec_Wo = (const float*)d_in[24];
    const float* dec_ln2s = (const float*)d_in[25];
    const float* dec_ln2b = (const float*)d_in[26];
    const float* dec_W1 = (const float*)d_in[27];
    const float* dec_b1 = (const float*)d_in[28];
    const float* dec_W2 = (const float*)d_in[29];
    const float* dec_b2 = (const float*)d_in[30];
    const float* dec_lnfs = (const float*)d_in[31];
    const float* dec_lnfb = (const float*)d_in[32];
    const float* pix_W = (const float*)d_in[33];
    const float* pix_b = (const float*)d_in[34];

    char* ws = (char*)d_ws;
    unsigned short* patches = (unsigned short*)(ws + OFF_PATCH);
    float* Rx = (float*)(ws + OFF_X);
    unsigned short* Rln = (unsigned short*)(ws + OFF_LN);
    unsigned short* RqkvB = (unsigned short*)(ws + OFF_QKV);
    float* RqkvF = (float*)(ws + OFF_QKV);
    unsigned short* Rhid = (unsigned short*)(ws + OFF_HID);
    unsigned short* wp = (unsigned short*)(ws + OFF_WP);
    int* ord = (int*)(ws + OFF_ORD);
    float* part = (float*)(ws + OFF_PART);
    float* out = (float*)d_out;

    auto PACK = [&](const float* src, size_t wpo, int K, int N) {
        pack_w<<<dim3(N / 32, K / 32), 256, 0, stream>>>(src, wp + wpo, K, N);
    };
    PACK(patch_W, WP_PATCH, 768, 1024);
    for (int l = 0; l < 2; ++l) {
        PACK(enc_Wqkv + (size_t)l * 1024 * 3072, WP_ENC_QKV + (size_t)l * 3145728, 1024, 3072);
        PACK(enc_Wo + (size_t)l * 1024 * 1024, WP_ENC_WO + (size_t)l * 1048576, 1024, 1024);
        PACK(enc_W1 + (size_t)l * 1024 * 4096, WP_ENC_W1 + (size_t)l * 4194304, 1024, 4096);
        PACK(enc_W2 + (size_t)l * 4096 * 1024, WP_ENC_W2 + (size_t)l * 4194304, 4096, 1024);
    }
    PACK(e2d_W, WP_E2D, 1024, 512);
    PACK(dec_Wqkv, WP_DEC_QKV, 512, 1536);
    PACK(dec_Wo, WP_DEC_WO, 512, 512);
    PACK(dec_W1, WP_DEC_W1, 512, 2048);
    PACK(dec_W2, WP_DEC_W2, 2048, 512);
    PACK(pix_W, WP_PIX, 512, 1024);

    // tile choice: 256^2 when it yields >=192 blocks (fills >=75% of CUs), else 128^2
    auto GEMM = [&](int om, const unsigned short* A, size_t wpo, void* C, const float* bias,
                    int M, int N, int K) {
        const unsigned short* Bt = wp + wpo;
        int b256 = (N / 256) * ((M + 255) / 256);
        if (b256 >= 192) {
            dim3 g(N / 256, (M + 255) / 256);
            if (om == OM_BF16) gemm2<256, 8, OM_BF16><<<g, 512, 0, stream>>>(A, Bt, C, bias, M, N, K);
            else if (om == OM_F32) gemm2<256, 8, OM_F32><<<g, 512, 0, stream>>>(A, Bt, C, bias, M, N, K);
            else if (om == OM_ACC) gemm2<256, 8, OM_ACC><<<g, 512, 0, stream>>>(A, Bt, C, bias, M, N, K);
            else gemm2<256, 8, OM_GELU><<<g, 512, 0, stream>>>(A, Bt, C, bias, M, N, K);
        } else {
            dim3 g(N / 128, (M + 127) / 128);
            if (om == OM_BF16) gemm2<128, 4, OM_BF16><<<g, 256, 0, stream>>>(A, Bt, C, bias, M, N, K);
            else if (om == OM_F32) gemm2<128, 4, OM_F32><<<g, 256, 0, stream>>>(A, Bt, C, bias, M, N, K);
            else if (om == OM_ACC) gemm2<128, 4, OM_ACC><<<g, 256, 0, stream>>>(A, Bt, C, bias, M, N, K);
            else gemm2<128, 4, OM_GELU><<<g, 256, 0, stream>>>(A, Bt, C, bias, M, N, K);
        }
    };

    // 1) patchify (Xp bf16 in Rhid), patches = Xp @ patch_W + b  (bf16)
    patchify_kernel<<<4096, 256, 0, stream>>>(images, Rhid);
    GEMM(OM_BF16, Rhid, WP_PATCH, patches, patch_b, 12544, 1024, 768);
    // 2) argsort + gather unmasked (fp32 residual stream)
    argsort_kernel<<<64, 256, 0, stream>>>(rnd, ord);
    gather_unmasked<<<3136, 256, 0, stream>>>(patches, pos_emb, ord, Rx);

    // 3) encoder
    for (int l = 0; l < 2; ++l) {
        ln_kernel<1024><<<3136, 256, 0, stream>>>(Rx, Rln, enc_ln1s + l * 1024,
                                                  enc_ln1b + l * 1024);
        GEMM(OM_BF16, Rln, WP_ENC_QKV + (size_t)l * 3145728, RqkvB, nullptr, 3136, 3072, 1024);
        attn_mfma<49, 16, 4><<<64 * 16, 256, 0, stream>>>(RqkvB, Rhid);
        GEMM(OM_ACC, Rhid, WP_ENC_WO + (size_t)l * 1048576, Rx, nullptr, 3136, 1024, 1024);
        ln_kernel<1024><<<3136, 256, 0, stream>>>(Rx, Rln, enc_ln2s + l * 1024,
                                                  enc_ln2b + l * 1024);
        GEMM(OM_GELU, Rln, WP_ENC_W1 + (size_t)l * 4194304, Rhid, enc_b1 + l * 4096, 3136,
             4096, 1024);
        GEMM(OM_ACC, Rhid, WP_ENC_W2 + (size_t)l * 4194304, Rx, enc_b2 + l * 1024, 3136, 1024,
             4096);
    }
    ln_kernel<1024><<<3136, 256, 0, stream>>>(Rx, Rln, enc_lnfs, enc_lnfb);

    // 4) e2d -> dec_tok (f32, in QKV region), scatter into decoder residual (f32)
    GEMM(OM_F32, Rln, WP_E2D, RqkvF, e2d_b, 3136, 512, 1024);
    scatter_tokens<<<12544, 256, 0, stream>>>(RqkvF, dec_pos, mask_tok, ord, Rx);

    // 5) decoder
    ln_kernel<512><<<12544, 256, 0, stream>>>(Rx, Rln, dec_ln1s, dec_ln1b);
    GEMM(OM_BF16, Rln, WP_DEC_QKV, RqkvB, nullptr, 12544, 1536, 512);
    attn_mfma<196, 8, 8><<<64 * 8, 512, 0, stream>>>(RqkvB, Rhid);
    GEMM(OM_ACC, Rhid, WP_DEC_WO, Rx, nullptr, 12544, 512, 512);
    ln_kernel<512><<<12544, 256, 0, stream>>>(Rx, Rln, dec_ln2s, dec_ln2b);
    GEMM(OM_GELU, Rln, WP_DEC_W1, Rhid, dec_b1, 12544, 2048, 512);
    GEMM(OM_ACC, Rhid, WP_DEC_W2, Rx, dec_b2, 12544, 512, 2048);
    ln_kernel<512><<<12544, 256, 0, stream>>>(Rx, Rln, dec_lnfs, dec_lnfb);

    // 6) gather masked, pix head (pred f32 in QKV region), MSE
    gather_masked<<<9408, 256, 0, stream>>>(Rln, ord, Rhid);
    GEMM(OM_F32, Rhid, WP_PIX, RqkvF, pix_b, 9408, 1024, 512);
    loss_partial<<<4096, 256, 0, stream>>>(RqkvF, patches, ord, part);
    loss_final<<<1, 256, 0, stream>>>(part, out);
}

// Round 5
// 988.591 us; speedup vs baseline: 6.0688x; 1.0643x over previous
//
#include <hip/hip_runtime.h>

typedef __attribute__((ext_vector_type(8))) __bf16 bf16x8;
typedef __attribute__((ext_vector_type(4))) float f32x4;

// ---------------- workspace layout (byte offsets) ----------------
#define OFF_PATCH 0ull          // bf16 12544x1024
#define OFF_X     25690112ull   // f32  max(3200x1024, 12544x512)
#define OFF_LN    51380224ull   // bf16 max(3200x1024, 12544x512)
#define OFF_QKV   64225280ull   // bf16 qkv / f32 dec_tok / f32 pred
#define OFF_HID   103022592ull  // bf16 max(12544x2048)
#define OFF_WP    154402816ull  // bf16 packed transposed weights
#define OFF_ORD   214695936ull  // int 12544
#define OFF_PART  214746112ull  // f32 4096

// bf16-element offsets inside packed-weight region
#define WP_PATCH   0ull
#define WP_ENC_QKV 786432ull
#define WP_ENC_WO  7077888ull
#define WP_ENC_W1  9175040ull
#define WP_ENC_W2  17563648ull
#define WP_E2D     25952256ull
#define WP_DEC_QKV 26476544ull
#define WP_DEC_WO  27262976ull
#define WP_DEC_W1  27525120ull
#define WP_DEC_W2  28573696ull
#define WP_PIX     29622272ull

#define OM_BF16 0
#define OM_F32  1
#define OM_ACC  2
#define OM_GELU 3

__device__ __forceinline__ float b2f(unsigned short u) {
    return __uint_as_float(((unsigned int)u) << 16);
}
__device__ __forceinline__ unsigned short f2b(float f) {
    unsigned int x = __float_as_uint(f);
    x += 0x7fffu + ((x >> 16) & 1u);
    return (unsigned short)(x >> 16);
}
// gelu(x) = 0.5x(1+tanh(u)) = x * sigmoid(2u), u = 0.79788456(x + 0.044715 x^3)
__device__ __forceinline__ float gelu_f(float x) {
    float u2 = 1.5957691216057308f * x * (1.f + 0.044715f * x * x);
    return x / (1.f + __expf(-u2));
}
__device__ __forceinline__ void gload16(const void* g, void* l) {
    __builtin_amdgcn_global_load_lds((const __attribute__((address_space(1))) void*)g,
                                     (__attribute__((address_space(3))) void*)l, 16, 0, 0);
}

// ---------------- weight pack: W[K][N] f32 -> Wt[N][K] bf16 ----------------
__global__ __launch_bounds__(256) void pack_w(const float* __restrict__ in,
                                              unsigned short* __restrict__ out, int K, int N) {
    __shared__ float tile[32][33];
    int kt = blockIdx.y * 32, nt = blockIdx.x * 32;
    int tx = threadIdx.x & 31, ty = threadIdx.x >> 5;  // 32 x 8
#pragma unroll
    for (int i = 0; i < 32; i += 8) tile[ty + i][tx] = in[(size_t)(kt + ty + i) * N + nt + tx];
    __syncthreads();
#pragma unroll
    for (int i = 0; i < 32; i += 8)
        out[(size_t)(nt + ty + i) * K + kt + tx] = f2b(tile[tx][ty + i]);
}

// ---------------- patchify: images -> Xp bf16 [12544][768] ----------------
__global__ __launch_bounds__(256) void patchify_kernel(const float* __restrict__ img,
                                                       unsigned short* __restrict__ Xp) {
    const long long total = 12544ll * 768;
    for (long long e = (long long)blockIdx.x * 256 + threadIdx.x; e < total;
         e += (long long)gridDim.x * 256) {
        int row = (int)(e / 768), k = (int)(e % 768);
        int b = row / 196, pi = row % 196;
        int py = pi / 14, px = pi % 14;
        int r = k / 48, rem = k % 48;
        int c = rem / 3, ch = rem % 3;
        long long src = (((long long)(b * 224 + py * 16 + r)) * 224 + (px * 16 + c)) * 3 + ch;
        Xp[e] = f2b(img[src]);
    }
}

// ---------------- MFMA GEMM, 128x128 2-phase dbuf, XOR-swizzled LDS, split-K ----------------
// C[MxN] (+=) A[MxK](bf16) @ Bt[NxK](bf16)^T over K range [z*Kc, (z+1)*Kc).
// 4 waves (2x2), MR=4, NR=4. XCD-bijective block swizzle on the (x,y) plane.
template <int OM, bool ATOMIC>
__global__ __launch_bounds__(256) void gemm2(const unsigned short* __restrict__ A,
                                             const unsigned short* __restrict__ Bt,
                                             void* __restrict__ Cv,
                                             const float* __restrict__ bias,
                                             int M, int N, int K, int Kc) {
    __shared__ __align__(16) unsigned short As[2][128 * 64];
    __shared__ __align__(16) unsigned short Bs[2][128 * 64];
    const int tid = threadIdx.x, wave = tid >> 6, lane = tid & 63;
    // bijective XCD remap (m204): contiguous wg-chunks per XCD for L2 locality
    int nwg = gridDim.x * gridDim.y;
    int orig = blockIdx.y * gridDim.x + blockIdx.x;
    int q = nwg >> 3, r8 = nwg & 7, xcd = orig & 7, off = orig >> 3;
    int wg = (xcd < r8 ? xcd * (q + 1) : r8 * (q + 1) + (xcd - r8) * q) + off;
    const int brow = (wg / gridDim.x) * 128, bcol = (wg % gridDim.x) * 128;
    const int kBeg = blockIdx.z * Kc;
    const int fr = lane & 15, fq = lane >> 4;
    const int wr = (wave >> 1) * 64, wc = (wave & 1) * 64;
    const int srow = wave * 32 + (lane >> 3);
    const int sca = ((lane & 7) ^ (lane >> 3)) * 8;  // inverse-swizzled source col
    const unsigned short* Ag = A + (size_t)(brow + srow) * K + kBeg + sca;
    const unsigned short* Bg = Bt + (size_t)(bcol + srow) * K + kBeg + sca;

    f32x4 acc[4][4];
#pragma unroll
    for (int m = 0; m < 4; ++m)
#pragma unroll
        for (int n = 0; n < 4; ++n) acc[m][n] = (f32x4){0.f, 0.f, 0.f, 0.f};

    auto stage = [&](int buf, int k0) {
        unsigned short* AsW = &As[buf][(wave * 32) * 64];
        unsigned short* BsW = &Bs[buf][(wave * 32) * 64];
#pragma unroll
        for (int i = 0; i < 4; ++i) {
            gload16(Ag + (size_t)(i * 8) * K + k0, AsW + i * 8 * 64);
            gload16(Bg + (size_t)(i * 8) * K + k0, BsW + i * 8 * 64);
        }
    };
    auto compute = [&](int buf) {
        const char* ab = (const char*)&As[buf][0];
        const char* bb = (const char*)&Bs[buf][0];
        const int sw = (fr & 7) << 4;
#pragma unroll
        for (int kk = 0; kk < 2; ++kk) {
            bf16x8 af[4], bf[4];
#pragma unroll
            for (int m = 0; m < 4; ++m)
                af[m] = *(const bf16x8*)(ab + (wr + m * 16 + fr) * 128 +
                                         ((kk * 64 + fq * 16) ^ sw));
#pragma unroll
            for (int n = 0; n < 4; ++n)
                bf[n] = *(const bf16x8*)(bb + (wc + n * 16 + fr) * 128 +
                                         ((kk * 64 + fq * 16) ^ sw));
#pragma unroll
            for (int m = 0; m < 4; ++m)
#pragma unroll
                for (int n = 0; n < 4; ++n)
                    acc[m][n] = __builtin_amdgcn_mfma_f32_16x16x32_bf16(af[m], bf[n],
                                                                       acc[m][n], 0, 0, 0);
        }
    };

    const int nt = Kc >> 6;
    stage(0, 0);
    __syncthreads();
    int cur = 0;
    for (int t = 0; t < nt - 1; ++t) {
        stage(cur ^ 1, (t + 1) << 6);
        compute(cur);
        __syncthreads();
        cur ^= 1;
    }
    compute(cur);

    const bool addBias = (bias != nullptr) && (kBeg == 0);
#pragma unroll
    for (int m = 0; m < 4; ++m) {
        int rb = brow + wr + m * 16 + fq * 4;
#pragma unroll
        for (int r = 0; r < 4; ++r) {
            int row = rb + r;
            if (row < M) {
#pragma unroll
                for (int n = 0; n < 4; ++n) {
                    int col = bcol + wc + n * 16 + fr;
                    float v = acc[m][n][r];
                    if (addBias) v += bias[col];
                    size_t o = (size_t)row * N + col;
                    if constexpr (ATOMIC) atomicAdd((float*)Cv + o, v);
                    else if constexpr (OM == OM_BF16) ((unsigned short*)Cv)[o] = f2b(v);
                    else if constexpr (OM == OM_F32) ((float*)Cv)[o] = v;
                    else if constexpr (OM == OM_ACC) ((float*)Cv)[o] += v;
                    else ((unsigned short*)Cv)[o] = f2b(gelu_f(v));
                }
            }
        }
    }
}

// ---------------- MFMA attention: one block per (b,h) ----------------
template <int N, int H, int NW>
__global__ __launch_bounds__(NW * 64) void attn_mfma(const unsigned short* __restrict__ qkv,
                                                     unsigned short* __restrict__ out) {
    constexpr int Npad = ((N + 31) / 32) * 32;
    constexpr int NT = Npad / 16;
    constexpr int KS = Npad / 32;
    constexpr int PS = Npad + 8;
    constexpr int SQ = 3 * H * 64, SO = H * 64;
    __shared__ __align__(16) unsigned short Kl[Npad * 64];
    __shared__ __align__(16) unsigned short Vt[64 * PS];
    __shared__ __align__(16) unsigned short Pl[NW * 16 * PS];
    const int b = blockIdx.x / H, h = blockIdx.x % H;
    const unsigned short* base = qkv + (size_t)b * N * SQ;
    const int qoff = h * 64, koff = (H + h) * 64, voff = (2 * H + h) * 64;
    const int tid = threadIdx.x, wave = tid >> 6, lane = tid & 63;
    const int fr = lane & 15, fq = lane >> 4;

    for (int idx = tid; idx < Npad * 8; idx += NW * 64) {
        int row = idx >> 3, ch = idx & 7;
        uint4 v = {0u, 0u, 0u, 0u};
        if (row < N) v = *(const uint4*)(base + (size_t)row * SQ + koff + ch * 8);
        *(uint4*)((char*)Kl + row * 128 + ((ch * 16) ^ ((row & 7) << 4))) = v;
    }
    for (int idx = tid; idx < Npad * 32; idx += NW * 64) {
        int key = idx >> 5, d2 = (idx & 31) * 2;
        unsigned int v = 0;
        if (key < N) v = *(const unsigned int*)(base + (size_t)key * SQ + voff + d2);
        Vt[d2 * PS + key] = (unsigned short)(v & 0xffffu);
        Vt[(d2 + 1) * PS + key] = (unsigned short)(v >> 16);
    }
    __syncthreads();

    unsigned short* pw = Pl + wave * 16 * PS;
    for (int qt = wave; qt < NT; qt += NW) {
        const int q0 = qt * 16;
        int qr = q0 + fr;
        if (qr > N - 1) qr = N - 1;
        const unsigned short* qp = base + (size_t)qr * SQ + qoff + fq * 8;
        bf16x8 aq0 = *(const bf16x8*)qp;
        bf16x8 aq1 = *(const bf16x8*)(qp + 32);
        f32x4 sa[NT];
#pragma unroll
        for (int ct = 0; ct < NT; ++ct) sa[ct] = (f32x4){0.f, 0.f, 0.f, 0.f};
#pragma unroll
        for (int ct = 0; ct < NT; ++ct) {
            const char* kb = (const char*)Kl + (ct * 16 + fr) * 128;
            bf16x8 kf0 = *(const bf16x8*)(kb + ((fq * 16) ^ ((fr & 7) << 4)));
            bf16x8 kf1 = *(const bf16x8*)(kb + ((64 + fq * 16) ^ ((fr & 7) << 4)));
            sa[ct] = __builtin_amdgcn_mfma_f32_16x16x32_bf16(aq0, kf0, sa[ct], 0, 0, 0);
            sa[ct] = __builtin_amdgcn_mfma_f32_16x16x32_bf16(aq1, kf1, sa[ct], 0, 0, 0);
        }
        float mrow[4] = {-3e38f, -3e38f, -3e38f, -3e38f};
#pragma unroll
        for (int ct = 0; ct < NT; ++ct) {
            bool ok = (ct * 16 + fr) < N;
#pragma unroll
            for (int r = 0; r < 4; ++r) {
                float s = ok ? sa[ct][r] * 0.125f : -3e38f;
                sa[ct][r] = s;
                mrow[r] = fmaxf(mrow[r], s);
            }
        }
#pragma unroll
        for (int off = 1; off <= 8; off <<= 1)
#pragma unroll
            for (int r = 0; r < 4; ++r) mrow[r] = fmaxf(mrow[r], __shfl_xor(mrow[r], off));
        float ssum[4] = {0.f, 0.f, 0.f, 0.f};
#pragma unroll
        for (int ct = 0; ct < NT; ++ct)
#pragma unroll
            for (int r = 0; r < 4; ++r) {
                float p = __expf(sa[ct][r] - mrow[r]);
                sa[ct][r] = p;
                ssum[r] += p;
            }
#pragma unroll
        for (int off = 1; off <= 8; off <<= 1)
#pragma unroll
            for (int r = 0; r < 4; ++r) ssum[r] += __shfl_xor(ssum[r], off);
#pragma unroll
        for (int ct = 0; ct < NT; ++ct)
#pragma unroll
            for (int r = 0; r < 4; ++r)
                pw[(fq * 4 + r) * PS + ct * 16 + fr] = f2b(sa[ct][r]);
        f32x4 oa[4];
#pragma unroll
        for (int vt = 0; vt < 4; ++vt) oa[vt] = (f32x4){0.f, 0.f, 0.f, 0.f};
#pragma unroll
        for (int ks = 0; ks < KS; ++ks) {
            bf16x8 pa = *(const bf16x8*)(pw + fr * PS + ks * 32 + fq * 8);
#pragma unroll
            for (int vt = 0; vt < 4; ++vt) {
                bf16x8 vf = *(const bf16x8*)(&Vt[(vt * 16 + fr) * PS + ks * 32 + fq * 8]);
                oa[vt] = __builtin_amdgcn_mfma_f32_16x16x32_bf16(pa, vf, oa[vt], 0, 0, 0);
            }
        }
        float inv[4];
#pragma unroll
        for (int r = 0; r < 4; ++r) inv[r] = 1.f / ssum[r];
#pragma unroll
        for (int vt = 0; vt < 4; ++vt)
#pragma unroll
            for (int r = 0; r < 4; ++r) {
                int q = q0 + fq * 4 + r;
                if (q < N)
                    out[((size_t)b * N + q) * SO + h * 64 + vt * 16 + fr] =
                        f2b(oa[vt][r] * inv[r]);
            }
    }
}

// ---------------- stable argsort of 196 per batch ----------------
__global__ __launch_bounds__(256) void argsort_kernel(const float* __restrict__ rnd,
                                                      int* __restrict__ ord) {
    __shared__ float vals[196];
    int b = blockIdx.x, t = threadIdx.x;
    if (t < 196) vals[t] = rnd[b * 196 + t];
    __syncthreads();
    if (t < 196) {
        float v = vals[t];
        int rank = 0;
        for (int j = 0; j < 196; ++j) {
            float vj = vals[j];
            rank += (vj < v) || (vj == v && j < t);
        }
        ord[b * 196 + rank] = t;
    }
}

__global__ __launch_bounds__(256) void gather_unmasked(const unsigned short* __restrict__ patches,
                                                       const float* __restrict__ pos,
                                                       const int* __restrict__ ord,
                                                       float* __restrict__ xe) {
    int row = blockIdx.x;  // 0..3135
    int b = row / 49, i = row % 49;
    int src = ord[b * 196 + 147 + i];
    const unsigned short* pr = patches + ((size_t)(b * 196 + src) << 10);
    const float* pe = pos + ((size_t)src << 10);
    float* o = xe + ((size_t)row << 10);
    int d = threadIdx.x * 4;
    ushort4 pv = *(const ushort4*)(pr + d);
    float4 p4 = *(const float4*)(pe + d);
    float4 r;
    r.x = b2f(pv.x) + p4.x; r.y = b2f(pv.y) + p4.y;
    r.z = b2f(pv.z) + p4.z; r.w = b2f(pv.w) + p4.w;
    *(float4*)(o + d) = r;
}

// ---------------- LayerNorm: f32 in -> bf16 out ----------------
template <int L>
__global__ __launch_bounds__(256) void ln_kernel(const float* __restrict__ x,
                                                 unsigned short* __restrict__ y,
                                                 const float* __restrict__ sw,
                                                 const float* __restrict__ bw) {
    __shared__ float red[8];
    const int tid = threadIdx.x;
    const float* xr = x + (size_t)blockIdx.x * L;
    float sum = 0.f, sq = 0.f;
    for (int i = tid * 4; i < L; i += 1024) {
        float4 v = *(const float4*)(xr + i);
        sum += v.x + v.y + v.z + v.w;
        sq += v.x * v.x + v.y * v.y + v.z * v.z + v.w * v.w;
    }
    for (int off = 32; off; off >>= 1) {
        sum += __shfl_xor(sum, off);
        sq += __shfl_xor(sq, off);
    }
    int wave = tid >> 6, lane = tid & 63;
    if (lane == 0) { red[wave] = sum; red[4 + wave] = sq; }
    __syncthreads();
    float ts = red[0] + red[1] + red[2] + red[3];
    float tq = red[4] + red[5] + red[6] + red[7];
    float mean = ts / L;
    float inv = rsqrtf(tq / L - mean * mean + 1e-5f);
    unsigned short* yr = y + (size_t)blockIdx.x * L;
    for (int i = tid * 4; i < L; i += 1024) {
        float4 v = *(const float4*)(xr + i);
        float4 s4 = *(const float4*)(sw + i);
        float4 b4 = *(const float4*)(bw + i);
        ushort4 o;
        o.x = f2b((v.x - mean) * inv * s4.x + b4.x);
        o.y = f2b((v.y - mean) * inv * s4.y + b4.y);
        o.z = f2b((v.z - mean) * inv * s4.z + b4.z);
        o.w = f2b((v.w - mean) * inv * s4.w + b4.w);
        *(ushort4*)(yr + i) = o;
    }
}

__global__ __launch_bounds__(256) void scatter_tokens(const float* __restrict__ dec_tok,
                                                      const float* __restrict__ dec_pos,
                                                      const float* __restrict__ mask_tok,
                                                      const int* __restrict__ ord,
                                                      float* __restrict__ all_tok) {
    int e = blockIdx.x;  // 0..12543
    int b = e / 196, i = e % 196;
    int idx = ord[e];
    float* o = all_tok + ((size_t)(b * 196 + idx)) * 512;
    const float* dp = dec_pos + (size_t)idx * 512;
    int d = threadIdx.x * 4;
    if (d < 512) {
        float4 dv = *(const float4*)(dp + d);
        float4 sv;
        if (i < 147) sv = *(const float4*)(mask_tok + d);
        else sv = *(const float4*)(dec_tok + ((size_t)(b * 49 + (i - 147))) * 512 + d);
        float4 r = {sv.x + dv.x, sv.y + dv.y, sv.z + dv.z, sv.w + dv.w};
        *(float4*)(o + d) = r;
    }
}

__global__ __launch_bounds__(256) void gather_masked(const unsigned short* __restrict__ x,
                                                     const int* __restrict__ ord,
                                                     unsigned short* __restrict__ gm) {
    int r = blockIdx.x;  // 0..9407
    int b = r / 147, j = r % 147;
    int idx = ord[b * 196 + j];
    const unsigned short* src = x + ((size_t)(b * 196 + idx)) * 512;
    unsigned short* o = gm + (size_t)r * 512;
    int d = threadIdx.x * 4;
    if (d < 512) *(ushort4*)(o + d) = *(const ushort4*)(src + d);
}

__global__ __launch_bounds__(256) void loss_partial(const float* __restrict__ pred,
                                                    const unsigned short* __restrict__ patches,
                                                    const int* __restrict__ ord,
                                                    float* __restrict__ part) {
    __shared__ float red[8];
    float local = 0.f;
    const long long total = 9633792ll;  // 9408*1024
    for (long long e = (long long)blockIdx.x * 256 + threadIdx.x; e < total; e += 4096ll * 256) {
        int r = (int)(e >> 10), d = (int)(e & 1023);
        int b = r / 147, j = r % 147;
        int idx = ord[b * 196 + j];
        float t = b2f(patches[(((size_t)(b * 196 + idx)) << 10) + d]);
        float df = pred[e] - t;
        local += df * df;
    }
    for (int off = 32; off; off >>= 1) local += __shfl_xor(local, off);
    int wave = threadIdx.x >> 6, lane = threadIdx.x & 63;
    if (lane == 0) red[wave] = local;
    __syncthreads();
    if (threadIdx.x == 0) part[blockIdx.x] = red[0] + red[1] + red[2] + red[3];
}

__global__ __launch_bounds__(256) void loss_final(const float* __restrict__ part,
                                                  float* __restrict__ out) {
    __shared__ float red[8];
    float local = 0.f;
    for (int i = threadIdx.x; i < 4096; i += 256) local += part[i];
    for (int off = 32; off; off >>= 1) local += __shfl_xor(local, off);
    int wave = threadIdx.x >> 6, lane = threadIdx.x & 63;
    if (lane == 0) red[wave] = local;
    __syncthreads();
    if (threadIdx.x == 0) out[0] = (red[0] + red[1] + red[2] + red[3]) / 9633792.0f;
}

extern "C" void kernel_launch(void* const* d_in, const int* in_sizes, int n_in, void* d_out,
                              int out_size, void* d_ws, size_t ws_size, hipStream_t stream) {
    const float* images = (const float*)d_in[0];
    const float* rnd = (const float*)d_in[1];
    const float* patch_W = (const float*)d_in[2];
    const float* patch_b = (const float*)d_in[3];
    const float* pos_emb = (const float*)d_in[4];
    const float* enc_ln1s = (const float*)d_in[5];
    const float* enc_ln1b = (const float*)d_in[6];
    const float* enc_Wqkv = (const float*)d_in[7];
    const float* enc_Wo = (const float*)d_in[8];
    const float* enc_ln2s = (const float*)d_in[9];
    const float* enc_ln2b = (const float*)d_in[10];
    const float* enc_W1 = (const float*)d_in[11];
    const float* enc_b1 = (const float*)d_in[12];
    const float* enc_W2 = (const float*)d_in[13];
    const float* enc_b2 = (const float*)d_in[14];
    const float* enc_lnfs = (const float*)d_in[15];
    const float* enc_lnfb = (const float*)d_in[16];
    const float* e2d_W = (const float*)d_in[17];
    const float* e2d_b = (const float*)d_in[18];
    const float* mask_tok = (const float*)d_in[19];
    const float* dec_pos = (const float*)d_in[20];
    const float* dec_ln1s = (const float*)d_in[21];
    const float* dec_ln1b = (const float*)d_in[22];
    const float* dec_Wqkv = (const float*)d_in[23];
    const float* dec_Wo = (const float*)d_in[24];
    const float* dec_ln2s = (const float*)d_in[25];
    const float* dec_ln2b = (const float*)d_in[26];
    const float* dec_W1 = (const float*)d_in[27];
    const float* dec_b1 = (const float*)d_in[28];
    const float* dec_W2 = (const float*)d_in[29];
    const float* dec_b2 = (const float*)d_in[30];
    const float* dec_lnfs = (const float*)d_in[31];
    const float* dec_lnfb = (const float*)d_in[32];
    const float* pix_W = (const float*)d_in[33];
    const float* pix_b = (const float*)d_in[34];

    char* ws = (char*)d_ws;
    unsigned short* patches = (unsigned short*)(ws + OFF_PATCH);
    float* Rx = (float*)(ws + OFF_X);
    unsigned short* Rln = (unsigned short*)(ws + OFF_LN);
    unsigned short* RqkvB = (unsigned short*)(ws + OFF_QKV);
    float* RqkvF = (float*)(ws + OFF_QKV);
    unsigned short* Rhid = (unsigned short*)(ws + OFF_HID);
    unsigned short* wp = (unsigned short*)(ws + OFF_WP);
    int* ord = (int*)(ws + OFF_ORD);
    float* part = (float*)(ws + OFF_PART);
    float* out = (float*)d_out;

    auto PACK = [&](const float* src, size_t wpo, int K, int N) {
        pack_w<<<dim3(N / 32, K / 32), 256, 0, stream>>>(src, wp + wpo, K, N);
    };
    PACK(patch_W, WP_PATCH, 768, 1024);
    for (int l = 0; l < 2; ++l) {
        PACK(enc_Wqkv + (size_t)l * 1024 * 3072, WP_ENC_QKV + (size_t)l * 3145728, 1024, 3072);
        PACK(enc_Wo + (size_t)l * 1024 * 1024, WP_ENC_WO + (size_t)l * 1048576, 1024, 1024);
        PACK(enc_W1 + (size_t)l * 1024 * 4096, WP_ENC_W1 + (size_t)l * 4194304, 1024, 4096);
        PACK(enc_W2 + (size_t)l * 4096 * 1024, WP_ENC_W2 + (size_t)l * 4194304, 4096, 1024);
    }
    PACK(e2d_W, WP_E2D, 1024, 512);
    PACK(dec_Wqkv, WP_DEC_QKV, 512, 1536);
    PACK(dec_Wo, WP_DEC_WO, 512, 512);
    PACK(dec_W1, WP_DEC_W1, 512, 2048);
    PACK(dec_W2, WP_DEC_W2, 2048, 512);
    PACK(pix_W, WP_PIX, 512, 1024);

    // S = split-K factor (ATOMIC accumulate when S>1; only valid for OM_ACC outputs)
    auto GEMM = [&](int om, const unsigned short* A, size_t wpo, void* C, const float* bias,
                    int M, int N, int K, int S) {
        const unsigned short* Bt = wp + wpo;
        dim3 g(N / 128, (M + 127) / 128, S);
        int Kc = K / S;
        if (S > 1) {
            gemm2<OM_ACC, true><<<g, 256, 0, stream>>>(A, Bt, C, bias, M, N, K, Kc);
        } else if (om == OM_BF16) {
            gemm2<OM_BF16, false><<<g, 256, 0, stream>>>(A, Bt, C, bias, M, N, K, Kc);
        } else if (om == OM_F32) {
            gemm2<OM_F32, false><<<g, 256, 0, stream>>>(A, Bt, C, bias, M, N, K, Kc);
        } else if (om == OM_ACC) {
            gemm2<OM_ACC, false><<<g, 256, 0, stream>>>(A, Bt, C, bias, M, N, K, Kc);
        } else {
            gemm2<OM_GELU, false><<<g, 256, 0, stream>>>(A, Bt, C, bias, M, N, K, Kc);
        }
    };

    // 1) patchify (Xp bf16 in Rhid), patches = Xp @ patch_W + b  (bf16)
    patchify_kernel<<<4096, 256, 0, stream>>>(images, Rhid);
    GEMM(OM_BF16, Rhid, WP_PATCH, patches, patch_b, 12544, 1024, 768, 1);
    // 2) argsort + gather unmasked (fp32 residual stream)
    argsort_kernel<<<64, 256, 0, stream>>>(rnd, ord);
    gather_unmasked<<<3136, 256, 0, stream>>>(patches, pos_emb, ord, Rx);

    // 3) encoder
    for (int l = 0; l < 2; ++l) {
        ln_kernel<1024><<<3136, 256, 0, stream>>>(Rx, Rln, enc_ln1s + l * 1024,
                                                  enc_ln1b + l * 1024);
        GEMM(OM_BF16, Rln, WP_ENC_QKV + (size_t)l * 3145728, RqkvB, nullptr, 3136, 3072, 1024, 1);
        attn_mfma<49, 16, 4><<<64 * 16, 256, 0, stream>>>(RqkvB, Rhid);
        GEMM(OM_ACC, Rhid, WP_ENC_WO + (size_t)l * 1048576, Rx, nullptr, 3136, 1024, 1024, 2);
        ln_kernel<1024><<<3136, 256, 0, stream>>>(Rx, Rln, enc_ln2s + l * 1024,
                                                  enc_ln2b + l * 1024);
        GEMM(OM_GELU, Rln, WP_ENC_W1 + (size_t)l * 4194304, Rhid, enc_b1 + l * 4096, 3136,
             4096, 1024, 1);
        GEMM(OM_ACC, Rhid, WP_ENC_W2 + (size_t)l * 4194304, Rx, enc_b2 + l * 1024, 3136, 1024,
             4096, 4);
    }
    ln_kernel<1024><<<3136, 256, 0, stream>>>(Rx, Rln, enc_lnfs, enc_lnfb);

    // 4) e2d -> dec_tok (f32, in QKV region), scatter into decoder residual (f32)
    GEMM(OM_F32, Rln, WP_E2D, RqkvF, e2d_b, 3136, 512, 1024, 1);
    scatter_tokens<<<12544, 256, 0, stream>>>(RqkvF, dec_pos, mask_tok, ord, Rx);

    // 5) decoder
    ln_kernel<512><<<12544, 256, 0, stream>>>(Rx, Rln, dec_ln1s, dec_ln1b);
    GEMM(OM_BF16, Rln, WP_DEC_QKV, RqkvB, nullptr, 12544, 1536, 512, 1);
    attn_mfma<196, 8, 8><<<64 * 8, 512, 0, stream>>>(RqkvB, Rhid);
    GEMM(OM_ACC, Rhid, WP_DEC_WO, Rx, nullptr, 12544, 512, 512, 1);
    ln_kernel<512><<<12544, 256, 0, stream>>>(Rx, Rln, dec_ln2s, dec_ln2b);
    GEMM(OM_GELU, Rln, WP_DEC_W1, Rhid, dec_b1, 12544, 2048, 512, 1);
    GEMM(OM_ACC, Rhid, WP_DEC_W2, Rx, dec_b2, 12544, 512, 2048, 2);
    ln_kernel<512><<<12544, 256, 0, stream>>>(Rx, Rln, dec_lnfs, dec_lnfb);

    // 6) gather masked, pix head (pred f32 in QKV region), MSE
    gather_masked<<<9408, 256, 0, stream>>>(Rln, ord, Rhid);
    GEMM(OM_F32, Rhid, WP_PIX, RqkvF, pix_b, 9408, 1024, 512, 1);
    loss_partial<<<4096, 256, 0, stream>>>(RqkvF, patches, ord, part);
    loss_final<<<1, 256, 0, stream>>>(part, out);
}

// Round 6
// 951.646 us; speedup vs baseline: 6.3044x; 1.0388x over previous
//
#include <hip/hip_runtime.h>

typedef __attribute__((ext_vector_type(8))) __bf16 bf16x8;
typedef __attribute__((ext_vector_type(4))) float f32x4;

// ---------------- workspace layout (byte offsets) ----------------
#define OFF_PATCH 0ull          // bf16 12544x1024
#define OFF_X     25690112ull   // f32  max(3200x1024, 12544x512)
#define OFF_LN    51380224ull   // bf16 max(3200x1024, 12544x512)
#define OFF_QKV   64225280ull   // bf16 qkv / f32 dec_tok / f32 pred
#define OFF_HID   103022592ull  // bf16 max(12544x2048)
#define OFF_WP    154402816ull  // bf16 packed transposed weights
#define OFF_ORD   214695936ull  // int 12544
#define OFF_PART  214746112ull  // f32 4096

// bf16-element offsets inside packed-weight region
#define WP_PATCH   0ull
#define WP_ENC_QKV 786432ull
#define WP_ENC_WO  7077888ull
#define WP_ENC_W1  9175040ull
#define WP_ENC_W2  17563648ull
#define WP_E2D     25952256ull
#define WP_DEC_QKV 26476544ull
#define WP_DEC_WO  27262976ull
#define WP_DEC_W1  27525120ull
#define WP_DEC_W2  28573696ull
#define WP_PIX     29622272ull

#define OM_BF16 0
#define OM_F32  1
#define OM_ACC  2
#define OM_GELU 3

__device__ __forceinline__ float b2f(unsigned short u) {
    return __uint_as_float(((unsigned int)u) << 16);
}
__device__ __forceinline__ unsigned short f2b(float f) {
    unsigned int x = __float_as_uint(f);
    x += 0x7fffu + ((x >> 16) & 1u);
    return (unsigned short)(x >> 16);
}
// gelu(x) = 0.5x(1+tanh(u)) = x * sigmoid(2u), u = 0.79788456(x + 0.044715 x^3)
__device__ __forceinline__ float gelu_f(float x) {
    float u2 = 1.5957691216057308f * x * (1.f + 0.044715f * x * x);
    return x / (1.f + __expf(-u2));
}
__device__ __forceinline__ void gload16(const void* g, void* l) {
    __builtin_amdgcn_global_load_lds((const __attribute__((address_space(1))) void*)g,
                                     (__attribute__((address_space(3))) void*)l, 16, 0, 0);
}

// ---------------- weight pack: W[K][N] f32 -> Wt[N][K] bf16 ----------------
__global__ __launch_bounds__(256) void pack_w(const float* __restrict__ in,
                                              unsigned short* __restrict__ out, int K, int N) {
    __shared__ float tile[32][33];
    int kt = blockIdx.y * 32, nt = blockIdx.x * 32;
    int tx = threadIdx.x & 31, ty = threadIdx.x >> 5;  // 32 x 8
#pragma unroll
    for (int i = 0; i < 32; i += 8) tile[ty + i][tx] = in[(size_t)(kt + ty + i) * N + nt + tx];
    __syncthreads();
#pragma unroll
    for (int i = 0; i < 32; i += 8)
        out[(size_t)(nt + ty + i) * K + kt + tx] = f2b(tile[tx][ty + i]);
}

// ---------------- patchify: images -> Xp bf16 [12544][768] ----------------
__global__ __launch_bounds__(256) void patchify_kernel(const float* __restrict__ img,
                                                       unsigned short* __restrict__ Xp) {
    const long long total = 12544ll * 768;
    for (long long e = (long long)blockIdx.x * 256 + threadIdx.x; e < total;
         e += (long long)gridDim.x * 256) {
        int row = (int)(e / 768), k = (int)(e % 768);
        int b = row / 196, pi = row % 196;
        int py = pi / 14, px = pi % 14;
        int r = k / 48, rem = k % 48;
        int c = rem / 3, ch = rem % 3;
        long long src = (((long long)(b * 224 + py * 16 + r)) * 224 + (px * 16 + c)) * 3 + ch;
        Xp[e] = f2b(img[src]);
    }
}

// ---------------- MFMA GEMM, 128x128, depth-2 prefetch, counted vmcnt ----------------
// C[MxN] (+=) A[MxK](bf16) @ Bt[NxK](bf16)^T over K range [z*Kc, (z+1)*Kc).
// 4 waves (2x2), MR=4, NR=4. XCD-bijective block swizzle on the (x,y) plane.
// Schedule: prologue stages tiles 0,1 (16 loads/wave). Per step: wait vmcnt(8)
// (oldest 8 = current buffer; newest 8 stay in flight) -> barrier -> compute ->
// barrier -> stage(t+2). vmcnt drains to 0 only on the final tile.
template <int OM, bool ATOMIC>
__global__ __launch_bounds__(256) void gemm2(const unsigned short* __restrict__ A,
                                             const unsigned short* __restrict__ Bt,
                                             void* __restrict__ Cv,
                                             const float* __restrict__ bias,
                                             int M, int N, int K, int Kc) {
    __shared__ __align__(16) unsigned short As[2][128 * 64];
    __shared__ __align__(16) unsigned short Bs[2][128 * 64];
    const int tid = threadIdx.x, wave = tid >> 6, lane = tid & 63;
    // bijective XCD remap (m204): contiguous wg-chunks per XCD for L2 locality
    int nwg = gridDim.x * gridDim.y;
    int orig = blockIdx.y * gridDim.x + blockIdx.x;
    int q = nwg >> 3, r8 = nwg & 7, xcd = orig & 7, off = orig >> 3;
    int wg = (xcd < r8 ? xcd * (q + 1) : r8 * (q + 1) + (xcd - r8) * q) + off;
    const int brow = (wg / gridDim.x) * 128, bcol = (wg % gridDim.x) * 128;
    const int kBeg = blockIdx.z * Kc;
    const int fr = lane & 15, fq = lane >> 4;
    const int wr = (wave >> 1) * 64, wc = (wave & 1) * 64;
    const int srow = wave * 32 + (lane >> 3);
    const int sca = ((lane & 7) ^ (lane >> 3)) * 8;  // inverse-swizzled source col
    const unsigned short* Ag = A + (size_t)(brow + srow) * K + kBeg + sca;
    const unsigned short* Bg = Bt + (size_t)(bcol + srow) * K + kBeg + sca;

    f32x4 acc[4][4];
#pragma unroll
    for (int m = 0; m < 4; ++m)
#pragma unroll
        for (int n = 0; n < 4; ++n) acc[m][n] = (f32x4){0.f, 0.f, 0.f, 0.f};

    auto stage = [&](int buf, int k0) {
        unsigned short* AsW = &As[buf][(wave * 32) * 64];
        unsigned short* BsW = &Bs[buf][(wave * 32) * 64];
#pragma unroll
        for (int i = 0; i < 4; ++i) {
            gload16(Ag + (size_t)(i * 8) * K + k0, AsW + i * 8 * 64);
            gload16(Bg + (size_t)(i * 8) * K + k0, BsW + i * 8 * 64);
        }
    };
    auto compute = [&](int buf) {
        const char* ab = (const char*)&As[buf][0];
        const char* bb = (const char*)&Bs[buf][0];
        const int sw = (fr & 7) << 4;
#pragma unroll
        for (int kk = 0; kk < 2; ++kk) {
            bf16x8 af[4], bf[4];
#pragma unroll
            for (int m = 0; m < 4; ++m)
                af[m] = *(const bf16x8*)(ab + (wr + m * 16 + fr) * 128 +
                                         ((kk * 64 + fq * 16) ^ sw));
#pragma unroll
            for (int n = 0; n < 4; ++n)
                bf[n] = *(const bf16x8*)(bb + (wc + n * 16 + fr) * 128 +
                                         ((kk * 64 + fq * 16) ^ sw));
#pragma unroll
            for (int m = 0; m < 4; ++m)
#pragma unroll
                for (int n = 0; n < 4; ++n)
                    acc[m][n] = __builtin_amdgcn_mfma_f32_16x16x32_bf16(af[m], bf[n],
                                                                       acc[m][n], 0, 0, 0);
        }
    };

    const int nt = Kc >> 6;
    stage(0, 0);
    if (nt > 1) stage(1, 64);
    int cur = 0;
    for (int t = 0; t < nt; ++t) {
        if (t < nt - 1)
            asm volatile("s_waitcnt vmcnt(8)" ::: "memory");
        else
            asm volatile("s_waitcnt vmcnt(0)" ::: "memory");
        __builtin_amdgcn_s_barrier();
        compute(cur);
        if (t + 2 < nt) {
            __builtin_amdgcn_s_barrier();
            stage(cur, (t + 2) << 6);
        }
        cur ^= 1;
    }

    const bool addBias = (bias != nullptr) && (kBeg == 0);
#pragma unroll
    for (int m = 0; m < 4; ++m) {
        int rb = brow + wr + m * 16 + fq * 4;
#pragma unroll
        for (int r = 0; r < 4; ++r) {
            int row = rb + r;
            if (row < M) {
#pragma unroll
                for (int n = 0; n < 4; ++n) {
                    int col = bcol + wc + n * 16 + fr;
                    float v = acc[m][n][r];
                    if (addBias) v += bias[col];
                    size_t o = (size_t)row * N + col;
                    if constexpr (ATOMIC) atomicAdd((float*)Cv + o, v);
                    else if constexpr (OM == OM_BF16) ((unsigned short*)Cv)[o] = f2b(v);
                    else if constexpr (OM == OM_F32) ((float*)Cv)[o] = v;
                    else if constexpr (OM == OM_ACC) ((float*)Cv)[o] += v;
                    else ((unsigned short*)Cv)[o] = f2b(gelu_f(v));
                }
            }
        }
    }
}

// ---------------- MFMA attention: one block per (b,h) ----------------
template <int N, int H, int NW>
__global__ __launch_bounds__(NW * 64) void attn_mfma(const unsigned short* __restrict__ qkv,
                                                     unsigned short* __restrict__ out) {
    constexpr int Npad = ((N + 31) / 32) * 32;
    constexpr int NT = Npad / 16;
    constexpr int KS = Npad / 32;
    constexpr int PS = Npad + 8;
    constexpr int SQ = 3 * H * 64, SO = H * 64;
    __shared__ __align__(16) unsigned short Kl[Npad * 64];
    __shared__ __align__(16) unsigned short Vt[64 * PS];
    __shared__ __align__(16) unsigned short Pl[NW * 16 * PS];
    const int b = blockIdx.x / H, h = blockIdx.x % H;
    const unsigned short* base = qkv + (size_t)b * N * SQ;
    const int qoff = h * 64, koff = (H + h) * 64, voff = (2 * H + h) * 64;
    const int tid = threadIdx.x, wave = tid >> 6, lane = tid & 63;
    const int fr = lane & 15, fq = lane >> 4;

    for (int idx = tid; idx < Npad * 8; idx += NW * 64) {
        int row = idx >> 3, ch = idx & 7;
        uint4 v = {0u, 0u, 0u, 0u};
        if (row < N) v = *(const uint4*)(base + (size_t)row * SQ + koff + ch * 8);
        *(uint4*)((char*)Kl + row * 128 + ((ch * 16) ^ ((row & 7) << 4))) = v;
    }
    for (int idx = tid; idx < Npad * 32; idx += NW * 64) {
        int key = idx >> 5, d2 = (idx & 31) * 2;
        unsigned int v = 0;
        if (key < N) v = *(const unsigned int*)(base + (size_t)key * SQ + voff + d2);
        Vt[d2 * PS + key] = (unsigned short)(v & 0xffffu);
        Vt[(d2 + 1) * PS + key] = (unsigned short)(v >> 16);
    }
    __syncthreads();

    unsigned short* pw = Pl + wave * 16 * PS;
    for (int qt = wave; qt < NT; qt += NW) {
        const int q0 = qt * 16;
        int qr = q0 + fr;
        if (qr > N - 1) qr = N - 1;
        const unsigned short* qp = base + (size_t)qr * SQ + qoff + fq * 8;
        bf16x8 aq0 = *(const bf16x8*)qp;
        bf16x8 aq1 = *(const bf16x8*)(qp + 32);
        f32x4 sa[NT];
#pragma unroll
        for (int ct = 0; ct < NT; ++ct) sa[ct] = (f32x4){0.f, 0.f, 0.f, 0.f};
#pragma unroll
        for (int ct = 0; ct < NT; ++ct) {
            const char* kb = (const char*)Kl + (ct * 16 + fr) * 128;
            bf16x8 kf0 = *(const bf16x8*)(kb + ((fq * 16) ^ ((fr & 7) << 4)));
            bf16x8 kf1 = *(const bf16x8*)(kb + ((64 + fq * 16) ^ ((fr & 7) << 4)));
            sa[ct] = __builtin_amdgcn_mfma_f32_16x16x32_bf16(aq0, kf0, sa[ct], 0, 0, 0);
            sa[ct] = __builtin_amdgcn_mfma_f32_16x16x32_bf16(aq1, kf1, sa[ct], 0, 0, 0);
        }
        float mrow[4] = {-3e38f, -3e38f, -3e38f, -3e38f};
#pragma unroll
        for (int ct = 0; ct < NT; ++ct) {
            bool ok = (ct * 16 + fr) < N;
#pragma unroll
            for (int r = 0; r < 4; ++r) {
                float s = ok ? sa[ct][r] * 0.125f : -3e38f;
                sa[ct][r] = s;
                mrow[r] = fmaxf(mrow[r], s);
            }
        }
#pragma unroll
        for (int off = 1; off <= 8; off <<= 1)
#pragma unroll
            for (int r = 0; r < 4; ++r) mrow[r] = fmaxf(mrow[r], __shfl_xor(mrow[r], off));
        float ssum[4] = {0.f, 0.f, 0.f, 0.f};
#pragma unroll
        for (int ct = 0; ct < NT; ++ct)
#pragma unroll
            for (int r = 0; r < 4; ++r) {
                float p = __expf(sa[ct][r] - mrow[r]);
                sa[ct][r] = p;
                ssum[r] += p;
            }
#pragma unroll
        for (int off = 1; off <= 8; off <<= 1)
#pragma unroll
            for (int r = 0; r < 4; ++r) ssum[r] += __shfl_xor(ssum[r], off);
#pragma unroll
        for (int ct = 0; ct < NT; ++ct)
#pragma unroll
            for (int r = 0; r < 4; ++r)
                pw[(fq * 4 + r) * PS + ct * 16 + fr] = f2b(sa[ct][r]);
        f32x4 oa[4];
#pragma unroll
        for (int vt = 0; vt < 4; ++vt) oa[vt] = (f32x4){0.f, 0.f, 0.f, 0.f};
#pragma unroll
        for (int ks = 0; ks < KS; ++ks) {
            bf16x8 pa = *(const bf16x8*)(pw + fr * PS + ks * 32 + fq * 8);
#pragma unroll
            for (int vt = 0; vt < 4; ++vt) {
                bf16x8 vf = *(const bf16x8*)(&Vt[(vt * 16 + fr) * PS + ks * 32 + fq * 8]);
                oa[vt] = __builtin_amdgcn_mfma_f32_16x16x32_bf16(pa, vf, oa[vt], 0, 0, 0);
            }
        }
        float inv[4];
#pragma unroll
        for (int r = 0; r < 4; ++r) inv[r] = 1.f / ssum[r];
#pragma unroll
        for (int vt = 0; vt < 4; ++vt)
#pragma unroll
            for (int r = 0; r < 4; ++r) {
                int q = q0 + fq * 4 + r;
                if (q < N)
                    out[((size_t)b * N + q) * SO + h * 64 + vt * 16 + fr] =
                        f2b(oa[vt][r] * inv[r]);
            }
    }
}

// ---------------- stable argsort of 196 per batch ----------------
__global__ __launch_bounds__(256) void argsort_kernel(const float* __restrict__ rnd,
                                                      int* __restrict__ ord) {
    __shared__ float vals[196];
    int b = blockIdx.x, t = threadIdx.x;
    if (t < 196) vals[t] = rnd[b * 196 + t];
    __syncthreads();
    if (t < 196) {
        float v = vals[t];
        int rank = 0;
        for (int j = 0; j < 196; ++j) {
            float vj = vals[j];
            rank += (vj < v) || (vj == v && j < t);
        }
        ord[b * 196 + rank] = t;
    }
}

__global__ __launch_bounds__(256) void gather_unmasked(const unsigned short* __restrict__ patches,
                                                       const float* __restrict__ pos,
                                                       const int* __restrict__ ord,
                                                       float* __restrict__ xe) {
    int row = blockIdx.x;  // 0..3135
    int b = row / 49, i = row % 49;
    int src = ord[b * 196 + 147 + i];
    const unsigned short* pr = patches + ((size_t)(b * 196 + src) << 10);
    const float* pe = pos + ((size_t)src << 10);
    float* o = xe + ((size_t)row << 10);
    int d = threadIdx.x * 4;
    ushort4 pv = *(const ushort4*)(pr + d);
    float4 p4 = *(const float4*)(pe + d);
    float4 r;
    r.x = b2f(pv.x) + p4.x; r.y = b2f(pv.y) + p4.y;
    r.z = b2f(pv.z) + p4.z; r.w = b2f(pv.w) + p4.w;
    *(float4*)(o + d) = r;
}

// ---------------- LayerNorm: f32 in -> bf16 out ----------------
template <int L>
__global__ __launch_bounds__(256) void ln_kernel(const float* __restrict__ x,
                                                 unsigned short* __restrict__ y,
                                                 const float* __restrict__ sw,
                                                 const float* __restrict__ bw) {
    __shared__ float red[8];
    const int tid = threadIdx.x;
    const float* xr = x + (size_t)blockIdx.x * L;
    float sum = 0.f, sq = 0.f;
    for (int i = tid * 4; i < L; i += 1024) {
        float4 v = *(const float4*)(xr + i);
        sum += v.x + v.y + v.z + v.w;
        sq += v.x * v.x + v.y * v.y + v.z * v.z + v.w * v.w;
    }
    for (int off = 32; off; off >>= 1) {
        sum += __shfl_xor(sum, off);
        sq += __shfl_xor(sq, off);
    }
    int wave = tid >> 6, lane = tid & 63;
    if (lane == 0) { red[wave] = sum; red[4 + wave] = sq; }
    __syncthreads();
    float ts = red[0] + red[1] + red[2] + red[3];
    float tq = red[4] + red[5] + red[6] + red[7];
    float mean = ts / L;
    float inv = rsqrtf(tq / L - mean * mean + 1e-5f);
    unsigned short* yr = y + (size_t)blockIdx.x * L;
    for (int i = tid * 4; i < L; i += 1024) {
        float4 v = *(const float4*)(xr + i);
        float4 s4 = *(const float4*)(sw + i);
        float4 b4 = *(const float4*)(bw + i);
        ushort4 o;
        o.x = f2b((v.x - mean) * inv * s4.x + b4.x);
        o.y = f2b((v.y - mean) * inv * s4.y + b4.y);
        o.z = f2b((v.z - mean) * inv * s4.z + b4.z);
        o.w = f2b((v.w - mean) * inv * s4.w + b4.w);
        *(ushort4*)(yr + i) = o;
    }
}

__global__ __launch_bounds__(256) void scatter_tokens(const float* __restrict__ dec_tok,
                                                      const float* __restrict__ dec_pos,
                                                      const float* __restrict__ mask_tok,
                                                      const int* __restrict__ ord,
                                                      float* __restrict__ all_tok) {
    int e = blockIdx.x;  // 0..12543
    int b = e / 196, i = e % 196;
    int idx = ord[e];
    float* o = all_tok + ((size_t)(b * 196 + idx)) * 512;
    const float* dp = dec_pos + (size_t)idx * 512;
    int d = threadIdx.x * 4;
    if (d < 512) {
        float4 dv = *(const float4*)(dp + d);
        float4 sv;
        if (i < 147) sv = *(const float4*)(mask_tok + d);
        else sv = *(const float4*)(dec_tok + ((size_t)(b * 49 + (i - 147))) * 512 + d);
        float4 r = {sv.x + dv.x, sv.y + dv.y, sv.z + dv.z, sv.w + dv.w};
        *(float4*)(o + d) = r;
    }
}

__global__ __launch_bounds__(256) void gather_masked(const unsigned short* __restrict__ x,
                                                     const int* __restrict__ ord,
                                                     unsigned short* __restrict__ gm) {
    int r = blockIdx.x;  // 0..9407
    int b = r / 147, j = r % 147;
    int idx = ord[b * 196 + j];
    const unsigned short* src = x + ((size_t)(b * 196 + idx)) * 512;
    unsigned short* o = gm + (size_t)r * 512;
    int d = threadIdx.x * 4;
    if (d < 512) *(ushort4*)(o + d) = *(const ushort4*)(src + d);
}

__global__ __launch_bounds__(256) void loss_partial(const float* __restrict__ pred,
                                                    const unsigned short* __restrict__ patches,
                                                    const int* __restrict__ ord,
                                                    float* __restrict__ part) {
    __shared__ float red[8];
    float local = 0.f;
    const long long total = 9633792ll;  // 9408*1024
    for (long long e = (long long)blockIdx.x * 256 + threadIdx.x; e < total; e += 4096ll * 256) {
        int r = (int)(e >> 10), d = (int)(e & 1023);
        int b = r / 147, j = r % 147;
        int idx = ord[b * 196 + j];
        float t = b2f(patches[(((size_t)(b * 196 + idx)) << 10) + d]);
        float df = pred[e] - t;
        local += df * df;
    }
    for (int off = 32; off; off >>= 1) local += __shfl_xor(local, off);
    int wave = threadIdx.x >> 6, lane = threadIdx.x & 63;
    if (lane == 0) red[wave] = local;
    __syncthreads();
    if (threadIdx.x == 0) part[blockIdx.x] = red[0] + red[1] + red[2] + red[3];
}

__global__ __launch_bounds__(256) void loss_final(const float* __restrict__ part,
                                                  float* __restrict__ out) {
    __shared__ float red[8];
    float local = 0.f;
    for (int i = threadIdx.x; i < 4096; i += 256) local += part[i];
    for (int off = 32; off; off >>= 1) local += __shfl_xor(local, off);
    int wave = threadIdx.x >> 6, lane = threadIdx.x & 63;
    if (lane == 0) red[wave] = local;
    __syncthreads();
    if (threadIdx.x == 0) out[0] = (red[0] + red[1] + red[2] + red[3]) / 9633792.0f;
}

extern "C" void kernel_launch(void* const* d_in, const int* in_sizes, int n_in, void* d_out,
                              int out_size, void* d_ws, size_t ws_size, hipStream_t stream) {
    const float* images = (const float*)d_in[0];
    const float* rnd = (const float*)d_in[1];
    const float* patch_W = (const float*)d_in[2];
    const float* patch_b = (const float*)d_in[3];
    const float* pos_emb = (const float*)d_in[4];
    const float* enc_ln1s = (const float*)d_in[5];
    const float* enc_ln1b = (const float*)d_in[6];
    const float* enc_Wqkv = (const float*)d_in[7];
    const float* enc_Wo = (const float*)d_in[8];
    const float* enc_ln2s = (const float*)d_in[9];
    const float* enc_ln2b = (const float*)d_in[10];
    const float* enc_W1 = (const float*)d_in[11];
    const float* enc_b1 = (const float*)d_in[12];
    const float* enc_W2 = (const float*)d_in[13];
    const float* enc_b2 = (const float*)d_in[14];
    const float* enc_lnfs = (const float*)d_in[15];
    const float* enc_lnfb = (const float*)d_in[16];
    const float* e2d_W = (const float*)d_in[17];
    const float* e2d_b = (const float*)d_in[18];
    const float* mask_tok = (const float*)d_in[19];
    const float* dec_pos = (const float*)d_in[20];
    const float* dec_ln1s = (const float*)d_in[21];
    const float* dec_ln1b = (const float*)d_in[22];
    const float* dec_Wqkv = (const float*)d_in[23];
    const float* dec_Wo = (const float*)d_in[24];
    const float* dec_ln2s = (const float*)d_in[25];
    const float* dec_ln2b = (const float*)d_in[26];
    const float* dec_W1 = (const float*)d_in[27];
    const float* dec_b1 = (const float*)d_in[28];
    const float* dec_W2 = (const float*)d_in[29];
    const float* dec_b2 = (const float*)d_in[30];
    const float* dec_lnfs = (const float*)d_in[31];
    const float* dec_lnfb = (const float*)d_in[32];
    const float* pix_W = (const float*)d_in[33];
    const float* pix_b = (const float*)d_in[34];

    char* ws = (char*)d_ws;
    unsigned short* patches = (unsigned short*)(ws + OFF_PATCH);
    float* Rx = (float*)(ws + OFF_X);
    unsigned short* Rln = (unsigned short*)(ws + OFF_LN);
    unsigned short* RqkvB = (unsigned short*)(ws + OFF_QKV);
    float* RqkvF = (float*)(ws + OFF_QKV);
    unsigned short* Rhid = (unsigned short*)(ws + OFF_HID);
    unsigned short* wp = (unsigned short*)(ws + OFF_WP);
    int* ord = (int*)(ws + OFF_ORD);
    float* part = (float*)(ws + OFF_PART);
    float* out = (float*)d_out;

    auto PACK = [&](const float* src, size_t wpo, int K, int N) {
        pack_w<<<dim3(N / 32, K / 32), 256, 0, stream>>>(src, wp + wpo, K, N);
    };
    PACK(patch_W, WP_PATCH, 768, 1024);
    for (int l = 0; l < 2; ++l) {
        PACK(enc_Wqkv + (size_t)l * 1024 * 3072, WP_ENC_QKV + (size_t)l * 3145728, 1024, 3072);
        PACK(enc_Wo + (size_t)l * 1024 * 1024, WP_ENC_WO + (size_t)l * 1048576, 1024, 1024);
        PACK(enc_W1 + (size_t)l * 1024 * 4096, WP_ENC_W1 + (size_t)l * 4194304, 1024, 4096);
        PACK(enc_W2 + (size_t)l * 4096 * 1024, WP_ENC_W2 + (size_t)l * 4194304, 4096, 1024);
    }
    PACK(e2d_W, WP_E2D, 1024, 512);
    PACK(dec_Wqkv, WP_DEC_QKV, 512, 1536);
    PACK(dec_Wo, WP_DEC_WO, 512, 512);
    PACK(dec_W1, WP_DEC_W1, 512, 2048);
    PACK(dec_W2, WP_DEC_W2, 2048, 512);
    PACK(pix_W, WP_PIX, 512, 1024);

    // S = split-K factor (ATOMIC accumulate when S>1; only valid for OM_ACC outputs)
    auto GEMM = [&](int om, const unsigned short* A, size_t wpo, void* C, const float* bias,
                    int M, int N, int K, int S) {
        const unsigned short* Bt = wp + wpo;
        dim3 g(N / 128, (M + 127) / 128, S);
        int Kc = K / S;
        if (S > 1) {
            gemm2<OM_ACC, true><<<g, 256, 0, stream>>>(A, Bt, C, bias, M, N, K, Kc);
        } else if (om == OM_BF16) {
            gemm2<OM_BF16, false><<<g, 256, 0, stream>>>(A, Bt, C, bias, M, N, K, Kc);
        } else if (om == OM_F32) {
            gemm2<OM_F32, false><<<g, 256, 0, stream>>>(A, Bt, C, bias, M, N, K, Kc);
        } else if (om == OM_ACC) {
            gemm2<OM_ACC, false><<<g, 256, 0, stream>>>(A, Bt, C, bias, M, N, K, Kc);
        } else {
            gemm2<OM_GELU, false><<<g, 256, 0, stream>>>(A, Bt, C, bias, M, N, K, Kc);
        }
    };

    // 1) patchify (Xp bf16 in Rhid), patches = Xp @ patch_W + b  (bf16)
    patchify_kernel<<<4096, 256, 0, stream>>>(images, Rhid);
    GEMM(OM_BF16, Rhid, WP_PATCH, patches, patch_b, 12544, 1024, 768, 1);
    // 2) argsort + gather unmasked (fp32 residual stream)
    argsort_kernel<<<64, 256, 0, stream>>>(rnd, ord);
    gather_unmasked<<<3136, 256, 0, stream>>>(patches, pos_emb, ord, Rx);

    // 3) encoder
    for (int l = 0; l < 2; ++l) {
        ln_kernel<1024><<<3136, 256, 0, stream>>>(Rx, Rln, enc_ln1s + l * 1024,
                                                  enc_ln1b + l * 1024);
        GEMM(OM_BF16, Rln, WP_ENC_QKV + (size_t)l * 3145728, RqkvB, nullptr, 3136, 3072, 1024, 1);
        attn_mfma<49, 16, 4><<<64 * 16, 256, 0, stream>>>(RqkvB, Rhid);
        GEMM(OM_ACC, Rhid, WP_ENC_WO + (size_t)l * 1048576, Rx, nullptr, 3136, 1024, 1024, 2);
        ln_kernel<1024><<<3136, 256, 0, stream>>>(Rx, Rln, enc_ln2s + l * 1024,
                                                  enc_ln2b + l * 1024);
        GEMM(OM_GELU, Rln, WP_ENC_W1 + (size_t)l * 4194304, Rhid, enc_b1 + l * 4096, 3136,
             4096, 1024, 1);
        GEMM(OM_ACC, Rhid, WP_ENC_W2 + (size_t)l * 4194304, Rx, enc_b2 + l * 1024, 3136, 1024,
             4096, 4);
    }
    ln_kernel<1024><<<3136, 256, 0, stream>>>(Rx, Rln, enc_lnfs, enc_lnfb);

    // 4) e2d -> dec_tok (f32, in QKV region), scatter into decoder residual (f32)
    GEMM(OM_F32, Rln, WP_E2D, RqkvF, e2d_b, 3136, 512, 1024, 1);
    scatter_tokens<<<12544, 256, 0, stream>>>(RqkvF, dec_pos, mask_tok, ord, Rx);

    // 5) decoder
    ln_kernel<512><<<12544, 256, 0, stream>>>(Rx, Rln, dec_ln1s, dec_ln1b);
    GEMM(OM_BF16, Rln, WP_DEC_QKV, RqkvB, nullptr, 12544, 1536, 512, 1);
    attn_mfma<196, 8, 8><<<64 * 8, 512, 0, stream>>>(RqkvB, Rhid);
    GEMM(OM_ACC, Rhid, WP_DEC_WO, Rx, nullptr, 12544, 512, 512, 1);
    ln_kernel<512><<<12544, 256, 0, stream>>>(Rx, Rln, dec_ln2s, dec_ln2b);
    GEMM(OM_GELU, Rln, WP_DEC_W1, Rhid, dec_b1, 12544, 2048, 512, 1);
    GEMM(OM_ACC, Rhid, WP_DEC_W2, Rx, dec_b2, 12544, 512, 2048, 2);
    ln_kernel<512><<<12544, 256, 0, stream>>>(Rx, Rln, dec_lnfs, dec_lnfb);

    // 6) gather masked, pix head (pred f32 in QKV region), MSE
    gather_masked<<<9408, 256, 0, stream>>>(Rln, ord, Rhid);
    GEMM(OM_F32, Rhid, WP_PIX, RqkvF, pix_b, 9408, 1024, 512, 1);
    loss_partial<<<4096, 256, 0, stream>>>(RqkvF, patches, ord, part);
    loss_final<<<1, 256, 0, stream>>>(part, out);
}